// Round 3
// baseline (5744.999 us; speedup 1.0000x reference)
//
#include <hip/hip_runtime.h>
#include <cstdint>
#include <cstddef>

typedef unsigned short ubf;   // bf16 bit pattern (internal use only)
typedef unsigned int   u32;
typedef unsigned long long u64;
typedef __attribute__((ext_vector_type(8))) short short8;
typedef __attribute__((ext_vector_type(4))) float f32x4;
typedef __attribute__((ext_vector_type(4))) float f4v;
typedef __attribute__((ext_vector_type(2))) float f2v;
typedef __attribute__((ext_vector_type(4))) unsigned short us4;

#define NEG_INF_F (-1000000000.0f)
#define FOURH 2048

// d_out element offsets in FLOAT32 elements (confirmed r8/r9).
#define ENC_SEG   8388608            // 64*256*512
#define REC_OFF   25165824
#define REC_SEG   8192000            // 64*256*500
#define MASK_OFF  49741824
#define LOGB_OFF  49774592
#define SAMB_OFF  49807360
#define LOGZ_OFF  49856512
#define SAMZ_OFF  49881088

// scratch inside recs[2] dead region (f32 elements from region base); r11 layout
// (every range dead before zdec-seg2 stripes land, except ROF in the verified
// stripe-free gap 896500..1024000).
#define SCR_P       0               // bf16[512][2048] = 524,288 f32
#define SCR_HBUF    524288          // u64[2][4][16][256] tagged h = 65,536 f32 (256KB)
#define SCR_MASKF   589824          // 16,384 f32
#define SCR_LOGCUM  606208          // 16,384 f32
#define SCR_PART    622592          // 131,072 f32
#define SCR_SBF     753664          // 16,384 f32
#define SCR_ROF     960000          // 32,768 f32 (stripe-free gap)

__device__ __forceinline__ float bf2f(ubf u){
  union { u32 i; float f; } v; v.i = ((u32)u) << 16; return v.f;
}
__device__ __forceinline__ ubf f2bf(float f){
  union { float f; u32 i; } v; v.f = f;
  u32 x = v.i;
  u32 r = (x + 0x7FFFu + ((x >> 16) & 1u)) >> 16;   // RNE
  return (ubf)r;
}
__device__ __forceinline__ float sigm(float x){
  return 1.0f / (1.0f + __expf(-x));
}
__device__ __forceinline__ float tanh_fast(float x){
  x = fminf(fmaxf(x, -20.0f), 20.0f);
  float e2 = __expf(2.0f * x);
  return (e2 - 1.0f) / (e2 + 1.0f);
}

// ---------------------------------------------------------------- init: clear tagged hbuf
// Graph replay leaves last launch's tags (max 768) in hbuf; seg2/t=255 polls
// want=768, so stale tags could false-trigger. Zero everything. Plain stores
// are fine: end-of-dispatch release writes back L2 (r11-proven).
__global__ void init_kernel(u64* hbuf){
  int idx = blockIdx.x * 256 + threadIdx.x;   // 0..16383
  hbuf[idx*2]     = 0ull;
  hbuf[idx*2 + 1] = 0ull;
}

// ---------------------------------------------------------------- GEMM (MFMA 16x16x32 bf16)
__global__ __launch_bounds__(256, 2) void gemm_kernel(
    const void* __restrict__ Aptr, int a_f32,
    const float* __restrict__ Bf, const float* __restrict__ bias,
    ubf* __restrict__ C, const float* __restrict__ wb2, float* __restrict__ part,
    int M, int N, int K, int relu, int mclamp)
{
  __shared__ __align__(16) ubf As[128*40];   // [128 rows][32 k + 8 pad]
  __shared__ __align__(16) ubf Bs[128*40];   // transposed: [128 n][32 k + 8 pad]
  int tid  = threadIdx.x;
  int bn   = blockIdx.x, bm = blockIdx.y;
  int w    = tid >> 6, lane = tid & 63, quad = lane >> 4, l16 = lane & 15;
  int wm   = w >> 1, wn = w & 1;

  f32x4 acc[4][4];
  #pragma unroll
  for (int i = 0; i < 4; i++)
    #pragma unroll
    for (int j = 0; j < 4; j++)
      #pragma unroll
      for (int r = 0; r < 4; r++) acc[i][j][r] = 0.0f;

  for (int k0 = 0; k0 < K; k0 += 32) {
    if (a_f32){
      const float* Af = (const float*)Aptr;
      #pragma unroll
      for (int h = 0; h < 4; h++){
        int v   = tid + h*256;          // 0..1023 float4 units
        int row = v >> 3, kc = (v & 7) * 4;
        int rm  = bm*128 + row;
        int ar  = rm < mclamp ? rm : mclamp;
        f4v q = *(const f4v*)(Af + (size_t)ar * K + k0 + kc);
        us4 s; s[0]=f2bf(q[0]); s[1]=f2bf(q[1]); s[2]=f2bf(q[2]); s[3]=f2bf(q[3]);
        *(us4*)&As[row*40 + kc] = s;
      }
    } else {
      const ubf* Ab = (const ubf*)Aptr;
      #pragma unroll
      for (int h = 0; h < 2; h++){
        int v   = tid + h*256;          // 0..511 vec8 units
        int row = v >> 2, kc = (v & 3) * 8;
        int rm  = bm*128 + row;
        int ar  = rm < mclamp ? rm : mclamp;
        uint4 q = *(const uint4*)(Ab + (size_t)ar * K + k0 + kc);
        *(uint4*)&As[row*40 + kc] = q;
      }
    }
    #pragma unroll
    for (int h = 0; h < 4; h++){
      int v  = tid + h*256;             // 0..1023 float4 units
      int kk = v >> 5, nn = (v & 31) * 4;
      f4v q = *(const f4v*)(Bf + (size_t)(k0 + kk) * N + bn*128 + nn);
      #pragma unroll
      for (int j = 0; j < 4; j++) Bs[(nn + j)*40 + kk] = f2bf(q[j]);
    }
    __syncthreads();
    short8 af[4], bfr[4];
    #pragma unroll
    for (int i = 0; i < 4; i++){
      int row = wm*64 + i*16 + l16;
      af[i]  = *(const short8*)&As[row*40 + quad*8];
      int col = wn*64 + i*16 + l16;
      bfr[i] = *(const short8*)&Bs[col*40 + quad*8];
    }
    #pragma unroll
    for (int i = 0; i < 4; i++)
      #pragma unroll
      for (int j = 0; j < 4; j++)
        acc[i][j] = __builtin_amdgcn_mfma_f32_16x16x32_bf16(af[i], bfr[j], acc[i][j], 0, 0, 0);
    __syncthreads();
  }
  if (!wb2){
    #pragma unroll
    for (int i = 0; i < 4; i++){
      #pragma unroll
      for (int j = 0; j < 4; j++){
        int n   = bn*128 + wn*64 + j*16 + l16;
        float bv = bias ? bias[n] : 0.0f;
        #pragma unroll
        for (int r = 0; r < 4; r++){
          int m   = bm*128 + wm*64 + i*16 + quad*4 + r;
          float vv = acc[i][j][r] + bv;
          if (relu) vv = fmaxf(vv, 0.0f);
          C[(size_t)m * N + n] = f2bf(vv);
        }
      }
    }
  } else {
    #pragma unroll
    for (int i = 0; i < 4; i++){
      f32x4 rp;
      #pragma unroll
      for (int r = 0; r < 4; r++) rp[r] = 0.0f;
      #pragma unroll
      for (int j = 0; j < 4; j++){
        int n   = bn*128 + wn*64 + j*16 + l16;
        float bv = bias[n];
        float wv = wb2[n];
        #pragma unroll
        for (int r = 0; r < 4; r++)
          rp[r] += fmaxf(acc[i][j][r] + bv, 0.0f) * wv;
      }
      #pragma unroll
      for (int off = 1; off < 16; off <<= 1)
        #pragma unroll
        for (int r = 0; r < 4; r++)
          rp[r] += __shfl_xor(rp[r], off, 64);
      if (l16 == 0){
        #pragma unroll
        for (int r = 0; r < 4; r++){
          int m = bm*128 + wm*64 + i*16 + quad*4 + r;
          part[(size_t)(bn*2 + wn)*16384 + m] = rp[r];
        }
      }
    }
  }
}

// ---------------------------------------------------------------- persistent masked-LSTM
// r13 protocol: tagged words (r11) + drain discipline (r10). Each h unit-pair
// is one aligned u64 {tag:32 | 2xbf16:32} sc1 store — single-copy atomic at
// L3 (HW-validated by r11's passing run), so the store IS the flag: readers
// observe data ~0.5 RT after issue, BEFORE the writer's own ack returns.
// r11's failure was the missing drain: the writer raced into 32KB poll sweeps
// that queued ahead of its pending stores -> commits straggled, readers swept
// 4-6x. Fix: per-thread `s_waitcnt vmcnt(0)` after the stores (cheaper than a
// barrier; vmcnt is per-wave so the wave's stores are ack'd before it polls).
// Barriers 3 -> 2: the dropped drain-barrier also protected ptile, but ptile
// rows are written+read by the SAME 16 threads of one wave (lockstep program
// order) — no cross-wave hazard. htile: prev-step MFMA reads complete before
// any thread passes syncB(t-1) < htile writes(t). ztile: reads(t) complete
// before any thread passes syncA(t+1) < ztile writes(t+1). Both safe.
__global__ __launch_bounds__(256, 1) void lstm_kernel(
    const ubf* __restrict__ Pt,      // [512(V pad)][4H] bf16, includes b_lstm
    const int* __restrict__ actions, // [B][T]
    const float* __restrict__ Whf,   // [H][4H] f32
    const float* __restrict__ mask,  // [B][T] f32 or null (seg 0)
    float* __restrict__ enc,         // d_out + seg*ENC_SEG (f32)
    u64* hbuf,                       // scratch: [2 parity][4 bg][16 row][256 word] tagged
    int seg)
{
  __shared__ __align__(16) ubf   htile[16*520];   // [16 b][512 + 8 pad]
  __shared__ __align__(16) ubf   ptile[16*136];   // [16 b][128 + 8 pad]
  __shared__ __align__(16) float ztile[16*132];   // [16 b][128 + 4 pad]

  int tid  = threadIdx.x;
  int wv   = tid >> 6;            // wave = gate index 0..3 (i,f,g,o)
  int lane = tid & 63, quad = lane >> 4, l16 = lane & 15;
  int bg   = blockIdx.x >> 4, cg = blockIdx.x & 15;
  int j0   = cg * 32;             // unit base

  // persistent Wh B-fragments: B[k][n], n = lane&15, k = quad*8+j
  short8 bfrag[2][16];
  #pragma unroll
  for (int h = 0; h < 2; h++){
    int col = wv*512 + j0 + h*16 + l16;
    #pragma unroll
    for (int kt = 0; kt < 16; kt++){
      short8 t8;
      #pragma unroll
      for (int j = 0; j < 8; j++){
        int k = kt*32 + quad*8 + j;
        t8[j] = (short)f2bf(Whf[(size_t)k * FOURH + col]);
      }
      bfrag[h][kt] = t8;
    }
  }

  float cst0 = 0.0f, cst1 = 0.0f;      // c-state for this thread's 2 (batch,unit) pairs
  int bl = tid >> 4;                   // local batch 0..15
  int up = (tid & 15) * 2;             // unit pair base within 32
  int bglob = bg*16 + bl;
  u32* htile32 = (u32*)htile;
  unsigned epoch0 = (unsigned)seg * 256u;

  for (int t = 0; t < 256; ++t){
    // stage P tile [16 b][4 gates x 32 units], gathered by action id
    // (L2-resident); issued first so its latency hides under the poll.
    // ptile row bl is wave-local (threads bl*16..bl*16+15): no barrier needed.
    {
      int act  = actions[(size_t)bglob * 256 + t];
      int colc = (tid & 15) * 8;
      int gate = colc >> 5, cw = colc & 31;
      uint4 q = *(const uint4*)(Pt + (size_t)act * FOURH + gate*512 + j0 + cw);
      *(uint4*)&ptile[bl*136 + colc] = q;
    }
    if (t > 0){
      // poll own 16 tagged words (word tid of rows 0..15, producer cg'=tid>>4).
      // The poll IS the data load: tag match => payload in hand.
      const u64* src = hbuf + (size_t)(((t+1)&1)*4 + bg) * (16*256);
      unsigned want = epoch0 + (unsigned)t;   // tag written at step t-1
      u32 tmp[16];
      unsigned got = 0;
      for (;;){
        #pragma unroll
        for (int i = 0; i < 16; i++){
          if (!(got & (1u << i))){
            u64 v = __hip_atomic_load(&src[tid + 256*i],
                                      __ATOMIC_RELAXED, __HIP_MEMORY_SCOPE_AGENT);
            if ((u32)(v >> 32) == want){ tmp[i] = (u32)v; got |= (1u << i); }
          }
        }
        if (got == 0xFFFFu) break;
        __builtin_amdgcn_s_sleep(1);   // back off between sweeps (r11 busy-spun)
      }
      #pragma unroll
      for (int i = 0; i < 16; i++)
        htile32[i*260 + tid] = tmp[i];     // row i = batch, 260 u32/row (padded)
    }
    __syncthreads();   // sync A: htile staged for this step

    f32x4 a0, a1;
    #pragma unroll
    for (int r = 0; r < 4; r++){ a0[r] = 0.0f; a1[r] = 0.0f; }
    if (t > 0){
      #pragma unroll
      for (int kt = 0; kt < 16; kt++){
        short8 af = *(const short8*)&htile[l16*520 + kt*32 + quad*8];
        a0 = __builtin_amdgcn_mfma_f32_16x16x32_bf16(af, bfrag[0][kt], a0, 0, 0, 0);
        a1 = __builtin_amdgcn_mfma_f32_16x16x32_bf16(af, bfrag[1][kt], a1, 0, 0, 0);
      }
    }
    // redistribute z via LDS so each thread gets matching i,f,g,o
    #pragma unroll
    for (int r = 0; r < 4; r++){
      ztile[(quad*4 + r)*132 + wv*32 + l16]      = a0[r];
      ztile[(quad*4 + r)*132 + wv*32 + 16 + l16] = a1[r];
    }
    __syncthreads();   // sync B: ztile ready for elementwise

    float m = mask ? mask[(size_t)bglob * 256 + t] : 1.0f;
    f2v ev;
    ubf hp[2];
    #pragma unroll
    for (int p = 0; p < 2; p++){
      int u = up + p;
      float zi = ztile[bl*132 +       u] + bf2f(ptile[bl*136 +       u]);
      float zf = ztile[bl*132 + 32 + u] + bf2f(ptile[bl*136 + 32 + u]);
      float zg = ztile[bl*132 + 64 + u] + bf2f(ptile[bl*136 + 64 + u]);
      float zo = ztile[bl*132 + 96 + u] + bf2f(ptile[bl*136 + 96 + u]);
      float is = sigm(zi), fs = sigm(zf), gt = tanh_fast(zg), os = sigm(zo);
      float cp = p ? cst1 : cst0;
      float cn = fs * cp + is * gt;
      float hn = os * tanh_fast(cn);
      ev[p] = hn;                       // enc records PRE-mask h (f32)
      float cm = m * cn;
      if (p) cst1 = cm; else cst0 = cm;
      hp[p] = f2bf(m * hn);             // masked h carried forward (bf16)
    }
    // tagged h store FIRST (latency-critical), then enc store, then drain.
    {
      u32 hword = (u32)hp[0] | ((u32)hp[1] << 16);
      u64 vv = ((u64)(epoch0 + (unsigned)t + 1u) << 32) | (u64)hword;
      u64* dst = hbuf + (size_t)((t&1)*4 + bg) * (16*256);
      __hip_atomic_store(&dst[(bl*512 + j0 + up) >> 1], vv,
                         __ATOMIC_RELAXED, __HIP_MEMORY_SCOPE_AGENT);
    }
    *(f2v*)(enc + ((size_t)bglob * 256 + t) * 512 + j0 + up) = ev;
    // per-thread drain: the wave's stores ack'd before it issues poll loads
    // (r11 lesson: without this, polls queue ahead of stores and commits
    // straggle). Readers observe the commit BEFORE this ack returns.
    asm volatile("s_waitcnt vmcnt(0)" ::: "memory");
  }
}

// ---------------------------------------------------------------- softmax + cumsum + mask update (per batch)
__global__ __launch_bounds__(256, 4) void softmax_kernel(
    const float* __restrict__ part, const float* __restrict__ bb2, const float* __restrict__ gum,
    float* __restrict__ lout,
    float* __restrict__ sbf, float* __restrict__ sbout,
    float* __restrict__ logcum, float* __restrict__ maskf, float* __restrict__ maskout,
    int seg)
{
  __shared__ float red[256];
  __shared__ float cs[256];
  int b = blockIdx.x, t = threadIdx.x;
  float raw = 0.0f;
  #pragma unroll
  for (int s = 0; s < 8; s++) raw += part[s*16384 + b*256 + t];
  float lg  = (t == 0) ? NEG_INF_F : (raw + bb2[0]);
  lout[b*256 + t] = lg;
  float x = lg + gum[b*256 + t];   // TEMP_B = 1
  red[t] = x; __syncthreads();
  for (int o = 128; o > 0; o >>= 1){ if (t < o) red[t] = fmaxf(red[t], red[t+o]); __syncthreads(); }
  float mx = red[0]; __syncthreads();
  float e = __expf(x - mx);
  red[t] = e; __syncthreads();
  for (int o = 128; o > 0; o >>= 1){ if (t < o) red[t] += red[t+o]; __syncthreads(); }
  float s = red[0];
  float sb = e / s;
  sbf[b*256 + t] = sb;
  sbout[b*256 + t] = sb;
  cs[t] = sb; __syncthreads();
  for (int o = 1; o < 256; o <<= 1){
    float v = cs[t];
    if (t >= o) v += cs[t - o];
    __syncthreads();
    cs[t] = v;
    __syncthreads();
  }
  float lc = logf(cs[t] + 1e-17f);
  float acc = (seg == 0) ? lc : (logcum[b*256 + t] + lc);
  logcum[b*256 + t] = acc;
  float mk = __expf(acc);
  maskf[b*256 + t] = mk;
  maskout[b*256 + t] = mk;
}

// ---------------------------------------------------------------- one-hot(lengths-1) (last segment)
__global__ void onehot_kernel(const int* __restrict__ lengths,
                              float* __restrict__ sbf, float* __restrict__ sbout)
{
  int b = blockIdx.x, t = threadIdx.x;
  float v = (t == (lengths[b] - 1)) ? 1.0f : 0.0f;
  sbf[b*256 + t] = v;
  sbout[b*256 + t] = v;
}

// ---------------------------------------------------------------- readout = sum_t enc[b,t]*sb[b,t+1]
__global__ __launch_bounds__(256, 4) void readout_kernel(
    const float* __restrict__ enc, const float* __restrict__ sbf, float* __restrict__ ro)
{
  __shared__ float sb[256];
  int b = blockIdx.x, tid = threadIdx.x;
  sb[tid] = sbf[b*256 + tid];
  __syncthreads();
  float a0 = 0.0f, a1 = 0.0f;
  for (int t = 0; t < 255; t++){
    float m = sb[t + 1];
    f2v q = *(const f2v*)(enc + ((size_t)b*256 + t)*512 + tid*2);
    a0 += m * q[0];
    a1 += m * q[1];
  }
  ro[b*512 + tid*2]     = a0;
  ro[b*512 + tid*2 + 1] = a1;
}

// ---------------------------------------------------------------- z-head + decoder (per batch)
__global__ __launch_bounds__(256, 2) void zdec_kernel(
    const float* __restrict__ ro,
    const float* __restrict__ Wz1, const float* __restrict__ bz1,
    const float* __restrict__ Wz2, const float* __restrict__ bz2,
    const float* __restrict__ epsz,
    const float* __restrict__ Wd1, const float* __restrict__ bd1,
    const float* __restrict__ Wd2, const float* __restrict__ bd2,
    float* __restrict__ lzout, float* __restrict__ szout, float* __restrict__ recseg)
{
  __shared__ float r[512], hz[512], lz[128], sz[64], hd[512];
  int b = blockIdx.x, tid = threadIdx.x;
  r[tid]       = ro[b*512 + tid];
  r[tid + 256] = ro[b*512 + tid + 256];
  __syncthreads();
  {
    float a0 = bz1[tid], a1 = bz1[tid + 256];
    for (int i = 0; i < 512; i++){
      float ri = r[i];
      a0 += ri * Wz1[(size_t)i*512 + tid];
      a1 += ri * Wz1[(size_t)i*512 + tid + 256];
    }
    hz[tid]       = fmaxf(a0, 0.0f);
    hz[tid + 256] = fmaxf(a1, 0.0f);
  }
  __syncthreads();
  if (tid < 128){
    float a = bz2[tid];
    for (int i = 0; i < 512; i++) a += hz[i] * Wz2[(size_t)i*128 + tid];
    lz[tid] = a;
    lzout[b*128 + tid] = a;
  }
  __syncthreads();
  if (tid < 64){
    float mu = lz[tid], lv = lz[64 + tid];
    float v = mu + __expf(0.5f * lv) * epsz[b*64 + tid];
    sz[tid] = v;
    szout[b*64 + tid] = v;
  }
  __syncthreads();
  {
    float a0 = bd1[tid], a1 = bd1[tid + 256];
    for (int l = 0; l < 64; l++){
      float s = sz[l];
      a0 += s * Wd1[l*512 + tid];
      a1 += s * Wd1[l*512 + tid + 256];
    }
    hd[tid]       = fmaxf(a0, 0.0f);
    hd[tid + 256] = fmaxf(a1, 0.0f);
  }
  __syncthreads();
  {
    float a0 = bd2[tid];
    float a1 = (tid < 244) ? bd2[tid + 256] : 0.0f;
    for (int h = 0; h < 512; h++){
      float hh = hd[h];
      a0 += hh * Wd2[(size_t)h*500 + tid];
      if (tid < 244) a1 += hh * Wd2[(size_t)h*500 + tid + 256];
    }
    recseg[(size_t)b*128000 + tid] = a0;
    if (tid < 244) recseg[(size_t)b*128000 + tid + 256] = a1;
  }
}

// ---------------------------------------------------------------- broadcast recs row (b,0) -> rows (b,t>=1)
__global__ void rec_kernel(float* __restrict__ outr)
{
  int bidx = blockIdx.x;
  int b = bidx >> 8, t = bidx & 255;
  if (t == 0) return;
  int tid = threadIdx.x;
  if (tid < 125){
    f4v q = *(const f4v*)(outr + (size_t)b*128000 + tid*4);
    *(f4v*)(outr + ((size_t)b*256 + t)*500 + tid*4) = q;
  }
}

// ---------------------------------------------------------------- launcher
extern "C" void kernel_launch(void* const* d_in, const int* in_sizes, int n_in,
                              void* d_out, int out_size, void* d_ws, size_t ws_size,
                              hipStream_t stream)
{
  const int*   actions = (const int*)d_in[0];
  const int*   lengths = (const int*)d_in[1];
  const float* gumbel  = (const float*)d_in[2];
  const float* epsz    = (const float*)d_in[3];
  const float* embed   = (const float*)d_in[4];
  const float* Wx      = (const float*)d_in[5];
  const float* Wh      = (const float*)d_in[6];
  const float* b_lstm  = (const float*)d_in[7];
  const float* Wz1     = (const float*)d_in[8];
  const float* bz1     = (const float*)d_in[9];
  const float* Wz2     = (const float*)d_in[10];
  const float* bz2     = (const float*)d_in[11];
  const float* Wb1     = (const float*)d_in[12];
  const float* bb1     = (const float*)d_in[13];
  const float* Wb2     = (const float*)d_in[14];
  const float* bb2     = (const float*)d_in[15];
  const float* Wd1     = (const float*)d_in[16];
  const float* bd1     = (const float*)d_in[17];
  const float* Wd2     = (const float*)d_in[18];
  const float* bd2     = (const float*)d_in[19];
  float* out = (float*)d_out;

  float* r2      = out + (size_t)REC_OFF + 2*(size_t)REC_SEG;
  ubf*   P       = (ubf*)(r2 + SCR_P);
  u64*   hbuf    = (u64*)(r2 + SCR_HBUF);
  float* maskf   = r2 + SCR_MASKF;
  float* logcum  = r2 + SCR_LOGCUM;
  float* partf   = r2 + SCR_PART;
  float* sbf     = r2 + SCR_SBF;
  float* rof     = r2 + SCR_ROF;

  hipLaunchKernelGGL(init_kernel, dim3(64), dim3(256), 0, stream, hbuf);

  hipLaunchKernelGGL(gemm_kernel, dim3(16, 4), dim3(256), 0, stream,
                     (const void*)embed, 1, Wx, b_lstm, P,
                     (const float*)nullptr, (float*)nullptr,
                     512, 2048, 512, 0, 499);

  for (int seg = 0; seg < 3; ++seg){
    hipLaunchKernelGGL(lstm_kernel, dim3(64), dim3(256), 0, stream,
                       P, actions, Wh,
                       (seg == 0) ? (const float*)nullptr : maskf,
                       out + (size_t)seg * ENC_SEG, hbuf, seg);
    const float* encc = out + (size_t)seg * ENC_SEG;
    if (seg < 2){
      hipLaunchKernelGGL(gemm_kernel, dim3(4, 128), dim3(256), 0, stream,
                         (const void*)encc, 1, Wb1, bb1, (ubf*)nullptr, Wb2, partf,
                         16384, 512, 512, 1, 16383);
      hipLaunchKernelGGL(softmax_kernel, dim3(64), dim3(256), 0, stream,
                         partf, bb2, gumbel + (size_t)seg * 16384,
                         out + LOGB_OFF + (size_t)seg * 16384,
                         sbf, out + SAMB_OFF + (size_t)seg * 16384,
                         logcum, maskf, out + MASK_OFF + (size_t)seg * 16384, seg);
    } else {
      hipLaunchKernelGGL(onehot_kernel, dim3(64), dim3(256), 0, stream,
                         lengths, sbf, out + SAMB_OFF + (size_t)seg * 16384);
    }
    hipLaunchKernelGGL(readout_kernel, dim3(64), dim3(256), 0, stream, encc, sbf, rof);
    hipLaunchKernelGGL(zdec_kernel, dim3(64), dim3(256), 0, stream,
                       rof, Wz1, bz1, Wz2, bz2, epsz + (size_t)seg * 4096,
                       Wd1, bd1, Wd2, bd2,
                       out + LOGZ_OFF + (size_t)seg * 8192,
                       out + SAMZ_OFF + (size_t)seg * 4096,
                       out + REC_OFF + (size_t)seg * REC_SEG);
    hipLaunchKernelGGL(rec_kernel, dim3(16384), dim3(128), 0, stream,
                       out + REC_OFF + (size_t)seg * REC_SEG);
  }
  (void)in_sizes; (void)n_in; (void)out_size; (void)d_ws; (void)ws_size;
}

// Round 4
// 3320.977 us; speedup vs baseline: 1.7299x; 1.7299x over previous
//
#include <hip/hip_runtime.h>
#include <cstdint>
#include <cstddef>

typedef unsigned short ubf;   // bf16 bit pattern (internal use only)
typedef unsigned int   u32;
typedef unsigned long long u64;
typedef __attribute__((ext_vector_type(8))) short short8;
typedef __attribute__((ext_vector_type(4))) float f32x4;
typedef __attribute__((ext_vector_type(4))) float f4v;
typedef __attribute__((ext_vector_type(2))) float f2v;
typedef __attribute__((ext_vector_type(4))) unsigned short us4;

#define NEG_INF_F (-1000000000.0f)
#define FOURH 2048

// d_out element offsets in FLOAT32 elements (confirmed r8/r9).
#define ENC_SEG   8388608            // 64*256*512
#define REC_OFF   25165824
#define REC_SEG   8192000            // 64*256*500
#define MASK_OFF  49741824
#define LOGB_OFF  49774592
#define SAMB_OFF  49807360
#define LOGZ_OFF  49856512
#define SAMZ_OFF  49881088

// scratch inside recs[2] dead region (f32 elements from region base); r10 layout.
#define SCR_P       0               // bf16[512][2048] = 524,288 f32
#define SCR_HBUF    524288          // bf16[2][4][16][512] = 32,768 f32
#define SCR_FLAGS   557056          // 1,024 f32 (uses 256 u32: [4 bg][16 cg][4 wave])
#define SCR_MASKF   558080          // 16,384 f32
#define SCR_LOGCUM  574464          // 16,384 f32
#define SCR_PART    590848          // 131,072 f32
#define SCR_SBF     721920          // 16,384 f32
#define SCR_ROF     960000          // 32,768 f32 (stripe-free gap)

__device__ __forceinline__ float bf2f(ubf u){
  union { u32 i; float f; } v; v.i = ((u32)u) << 16; return v.f;
}
__device__ __forceinline__ ubf f2bf(float f){
  union { float f; u32 i; } v; v.f = f;
  u32 x = v.i;
  u32 r = (x + 0x7FFFu + ((x >> 16) & 1u)) >> 16;   // RNE
  return (ubf)r;
}
__device__ __forceinline__ float sigm(float x){
  return 1.0f / (1.0f + __expf(-x));
}
__device__ __forceinline__ float tanh_fast(float x){
  x = fminf(fmaxf(x, -20.0f), 20.0f);
  float e2 = __expf(2.0f * x);
  return (e2 - 1.0f) / (e2 + 1.0f);
}

// ---------------------------------------------------------------- init flags
__global__ void init_kernel(u32* flags){
  flags[threadIdx.x] = 0u;   // 256 u32 = [4 bg][16 cg][4 wave]
}

// ---------------------------------------------------------------- GEMM (MFMA 16x16x32 bf16)
__global__ __launch_bounds__(256, 2) void gemm_kernel(
    const void* __restrict__ Aptr, int a_f32,
    const float* __restrict__ Bf, const float* __restrict__ bias,
    ubf* __restrict__ C, const float* __restrict__ wb2, float* __restrict__ part,
    int M, int N, int K, int relu, int mclamp)
{
  __shared__ __align__(16) ubf As[128*40];   // [128 rows][32 k + 8 pad]
  __shared__ __align__(16) ubf Bs[128*40];   // transposed: [128 n][32 k + 8 pad]
  int tid  = threadIdx.x;
  int bn   = blockIdx.x, bm = blockIdx.y;
  int w    = tid >> 6, lane = tid & 63, quad = lane >> 4, l16 = lane & 15;
  int wm   = w >> 1, wn = w & 1;

  f32x4 acc[4][4];
  #pragma unroll
  for (int i = 0; i < 4; i++)
    #pragma unroll
    for (int j = 0; j < 4; j++)
      #pragma unroll
      for (int r = 0; r < 4; r++) acc[i][j][r] = 0.0f;

  for (int k0 = 0; k0 < K; k0 += 32) {
    if (a_f32){
      const float* Af = (const float*)Aptr;
      #pragma unroll
      for (int h = 0; h < 4; h++){
        int v   = tid + h*256;          // 0..1023 float4 units
        int row = v >> 3, kc = (v & 7) * 4;
        int rm  = bm*128 + row;
        int ar  = rm < mclamp ? rm : mclamp;
        f4v q = *(const f4v*)(Af + (size_t)ar * K + k0 + kc);
        us4 s; s[0]=f2bf(q[0]); s[1]=f2bf(q[1]); s[2]=f2bf(q[2]); s[3]=f2bf(q[3]);
        *(us4*)&As[row*40 + kc] = s;
      }
    } else {
      const ubf* Ab = (const ubf*)Aptr;
      #pragma unroll
      for (int h = 0; h < 2; h++){
        int v   = tid + h*256;          // 0..511 vec8 units
        int row = v >> 2, kc = (v & 3) * 8;
        int rm  = bm*128 + row;
        int ar  = rm < mclamp ? rm : mclamp;
        uint4 q = *(const uint4*)(Ab + (size_t)ar * K + k0 + kc);
        *(uint4*)&As[row*40 + kc] = q;
      }
    }
    #pragma unroll
    for (int h = 0; h < 4; h++){
      int v  = tid + h*256;             // 0..1023 float4 units
      int kk = v >> 5, nn = (v & 31) * 4;
      f4v q = *(const f4v*)(Bf + (size_t)(k0 + kk) * N + bn*128 + nn);
      #pragma unroll
      for (int j = 0; j < 4; j++) Bs[(nn + j)*40 + kk] = f2bf(q[j]);
    }
    __syncthreads();
    short8 af[4], bfr[4];
    #pragma unroll
    for (int i = 0; i < 4; i++){
      int row = wm*64 + i*16 + l16;
      af[i]  = *(const short8*)&As[row*40 + quad*8];
      int col = wn*64 + i*16 + l16;
      bfr[i] = *(const short8*)&Bs[col*40 + quad*8];
    }
    #pragma unroll
    for (int i = 0; i < 4; i++)
      #pragma unroll
      for (int j = 0; j < 4; j++)
        acc[i][j] = __builtin_amdgcn_mfma_f32_16x16x32_bf16(af[i], bfr[j], acc[i][j], 0, 0, 0);
    __syncthreads();
  }
  if (!wb2){
    #pragma unroll
    for (int i = 0; i < 4; i++){
      #pragma unroll
      for (int j = 0; j < 4; j++){
        int n   = bn*128 + wn*64 + j*16 + l16;
        float bv = bias ? bias[n] : 0.0f;
        #pragma unroll
        for (int r = 0; r < 4; r++){
          int m   = bm*128 + wm*64 + i*16 + quad*4 + r;
          float vv = acc[i][j][r] + bv;
          if (relu) vv = fmaxf(vv, 0.0f);
          C[(size_t)m * N + n] = f2bf(vv);
        }
      }
    }
  } else {
    #pragma unroll
    for (int i = 0; i < 4; i++){
      f32x4 rp;
      #pragma unroll
      for (int r = 0; r < 4; r++) rp[r] = 0.0f;
      #pragma unroll
      for (int j = 0; j < 4; j++){
        int n   = bn*128 + wn*64 + j*16 + l16;
        float bv = bias[n];
        float wv = wb2[n];
        #pragma unroll
        for (int r = 0; r < 4; r++)
          rp[r] += fmaxf(acc[i][j][r] + bv, 0.0f) * wv;
      }
      #pragma unroll
      for (int off = 1; off < 16; off <<= 1)
        #pragma unroll
        for (int r = 0; r < 4; r++)
          rp[r] += __shfl_xor(rp[r], off, 64);
      if (l16 == 0){
        #pragma unroll
        for (int r = 0; r < 4; r++){
          int m = bm*128 + wm*64 + i*16 + quad*4 + r;
          part[(size_t)(bn*2 + wn)*16384 + m] = rp[r];
        }
      }
    }
  }
}

// ---------------------------------------------------------------- persistent masked-LSTM
// r14 = r12 protocol (proven 610us; flag + one-shot bulk load; r11/r13 showed
// tagged-poll floods the fabric at ~7 TB/s and is 2.6x slower) with the
// intra-block overhead shaved:
//  * PER-WAVE flags: vmcnt is per-wave, so each wave drains ITS own h-stores
//    (rows 4wv..4wv+3) and posts flags[bg][cg][wv]. The block-wide
//    drain-barrier and __threadfence_block are deleted (3 barriers -> 2).
//    Consumers poll all 4 wave-flags of their producer (two u64 loads, 16B).
//    Overwrite-safety transitivity is preserved: block X's h-write at step t
//    is preceded (program order) by X's syncA(t), which is preceded by ALL
//    X-threads' polls of ALL producers' 4 wave-flags(t); producer-wave flag(t)
//    is posted after that wave's bulk-read(t-1) of X's old slot. htile WAR:
//    wave's htile writes(t+1) come after its syncB(t), and all waves' MFMA(t)
//    htile reads complete before any wave passes syncB(t). ztile WAR: reads(t)
//    complete before syncA(t+1), writes(t+1) after it.
//  * busy-poll (no s_sleep): poll = 4 x 16B lines/block/sweep (~0.4 TB/s
//    fabric) — affordable; removes 64-cyc sleep quantization.
//  * MFMA accumulators split into kt 0..7 / 8..15 chains (two 8-deep
//    dependent chains instead of one 16-deep), summed at the end.
__global__ __launch_bounds__(256, 1) void lstm_kernel(
    const ubf* __restrict__ Pt,      // [512(V pad)][4H] bf16, includes b_lstm
    const int* __restrict__ actions, // [B][T]
    const float* __restrict__ Whf,   // [H][4H] f32
    const float* __restrict__ mask,  // [B][T] f32 or null (seg 0)
    float* __restrict__ enc,         // d_out + seg*ENC_SEG (f32)
    ubf* hbuf,                       // scratch: [2][4][16][512] bf16
    u32* flags,                      // scratch: [4 bg][16 cg][4 wave] u32
    int seg)
{
  __shared__ __align__(16) ubf   htile[16*520];   // [16 b][512 + 8 pad]
  __shared__ __align__(16) ubf   ptile[16*136];   // [16 b][128 + 8 pad]
  __shared__ __align__(16) float ztile[16*132];   // [16 b][128 + 4 pad]

  int tid  = threadIdx.x;
  int wv   = tid >> 6;            // wave = gate index 0..3 (i,f,g,o)
  int lane = tid & 63, quad = lane >> 4, l16 = lane & 15;
  int bg   = blockIdx.x >> 4, cg = blockIdx.x & 15;
  int j0   = cg * 32;             // unit base

  // persistent Wh B-fragments: B[k][n], n = lane&15, k = quad*8+j
  short8 bfrag[2][16];
  #pragma unroll
  for (int h = 0; h < 2; h++){
    int col = wv*512 + j0 + h*16 + l16;
    #pragma unroll
    for (int kt = 0; kt < 16; kt++){
      short8 t8;
      #pragma unroll
      for (int j = 0; j < 8; j++){
        int k = kt*32 + quad*8 + j;
        t8[j] = (short)f2bf(Whf[(size_t)k * FOURH + col]);
      }
      bfrag[h][kt] = t8;
    }
  }

  float cst0 = 0.0f, cst1 = 0.0f;      // c-state for this thread's 2 (batch,unit) pairs
  int bl = tid >> 4;                   // local batch 0..15
  int up = (tid & 15) * 2;             // unit pair base within 32
  int bglob = bg*16 + bl;
  u32* htile32 = (u32*)htile;
  unsigned epoch0 = (unsigned)seg * 256u;
  // 4 wave-flags of this thread's producer block (16B contiguous)
  const u64* fb = (const u64*)&flags[(bg*16 + (tid >> 4)) << 2];

  for (int t = 0; t < 256; ++t){
    // stage P tile [16 b][4 gates x 32 units], gathered by action id
    // (L2-resident); issued first so its latency hides under the flag poll.
    // ptile row bl is written+read by the same 16 lanes of one wave: no
    // cross-wave hazard.
    {
      int act  = actions[(size_t)bglob * 256 + t];
      int colc = (tid & 15) * 8;
      int gate = colc >> 5, cw = colc & 31;
      uint4 q = *(const uint4*)(Pt + (size_t)act * FOURH + gate*512 + j0 + cw);
      *(uint4*)&ptile[bl*136 + colc] = q;
    }
    if (t > 0){
      // busy-poll the producer's 4 wave-flags, then one-shot bulk load.
      unsigned tgt = epoch0 + (unsigned)t;
      for (;;){
        u64 f01 = __hip_atomic_load(fb,     __ATOMIC_RELAXED, __HIP_MEMORY_SCOPE_AGENT);
        u64 f23 = __hip_atomic_load(fb + 1, __ATOMIC_RELAXED, __HIP_MEMORY_SCOPE_AGENT);
        if ((u32)f01 >= tgt && (u32)(f01 >> 32) >= tgt &&
            (u32)f23 >= tgt && (u32)(f23 >> 32) >= tgt) break;
      }
      const u32* src = (const u32*)(hbuf + (size_t)(((t+1)&1)*4 + bg) * 16 * 512);
      u32 tmp[16];
      #pragma unroll
      for (int i = 0; i < 16; i++)
        tmp[i] = __hip_atomic_load(&src[tid + 256*i], __ATOMIC_RELAXED, __HIP_MEMORY_SCOPE_AGENT);
      #pragma unroll
      for (int i = 0; i < 16; i++)
        htile32[i*260 + tid] = tmp[i];     // row i = batch, 260 u32/row (padded)
    }
    __syncthreads();   // sync A: htile staged for this step

    f32x4 a0, a1, a2, a3;
    #pragma unroll
    for (int r = 0; r < 4; r++){ a0[r]=0.0f; a1[r]=0.0f; a2[r]=0.0f; a3[r]=0.0f; }
    if (t > 0){
      #pragma unroll
      for (int kt = 0; kt < 8; kt++){
        short8 af = *(const short8*)&htile[l16*520 + kt*32 + quad*8];
        a0 = __builtin_amdgcn_mfma_f32_16x16x32_bf16(af, bfrag[0][kt], a0, 0, 0, 0);
        a1 = __builtin_amdgcn_mfma_f32_16x16x32_bf16(af, bfrag[1][kt], a1, 0, 0, 0);
      }
      #pragma unroll
      for (int kt = 8; kt < 16; kt++){
        short8 af = *(const short8*)&htile[l16*520 + kt*32 + quad*8];
        a2 = __builtin_amdgcn_mfma_f32_16x16x32_bf16(af, bfrag[0][kt], a2, 0, 0, 0);
        a3 = __builtin_amdgcn_mfma_f32_16x16x32_bf16(af, bfrag[1][kt], a3, 0, 0, 0);
      }
      #pragma unroll
      for (int r = 0; r < 4; r++){ a0[r] += a2[r]; a1[r] += a3[r]; }
    }
    // redistribute z via LDS so each thread gets matching i,f,g,o
    #pragma unroll
    for (int r = 0; r < 4; r++){
      ztile[(quad*4 + r)*132 + wv*32 + l16]      = a0[r];
      ztile[(quad*4 + r)*132 + wv*32 + 16 + l16] = a1[r];
    }
    __syncthreads();   // sync B: ztile ready for elementwise

    float m = mask ? mask[(size_t)bglob * 256 + t] : 1.0f;
    f2v ev;
    ubf hp[2];
    #pragma unroll
    for (int p = 0; p < 2; p++){
      int u = up + p;
      float zi = ztile[bl*132 +       u] + bf2f(ptile[bl*136 +       u]);
      float zf = ztile[bl*132 + 32 + u] + bf2f(ptile[bl*136 + 32 + u]);
      float zg = ztile[bl*132 + 64 + u] + bf2f(ptile[bl*136 + 64 + u]);
      float zo = ztile[bl*132 + 96 + u] + bf2f(ptile[bl*136 + 96 + u]);
      float is = sigm(zi), fs = sigm(zf), gt = tanh_fast(zg), os = sigm(zo);
      float cp = p ? cst1 : cst0;
      float cn = fs * cp + is * gt;
      float hn = os * tanh_fast(cn);
      ev[p] = hn;                       // enc records PRE-mask h (f32)
      float cm = m * cn;
      if (p) cst1 = cm; else cst0 = cm;
      hp[p] = f2bf(m * hn);             // masked h carried forward (bf16)
    }
    // h store -> per-wave drain -> per-wave flag. The wave's lane0 posts
    // flags[bg][cg][wv] covering rows 4wv..4wv+3 (bl = tid>>4 spans exactly
    // 4 rows per wave).
    {
      u32 hword = (u32)hp[0] | ((u32)hp[1] << 16);
      u32* dst = (u32*)(hbuf + (size_t)((t&1)*4 + bg) * 16 * 512);
      __hip_atomic_store(&dst[(bl*512 + j0 + up) >> 1], hword,
                         __ATOMIC_RELAXED, __HIP_MEMORY_SCOPE_AGENT);
    }
    asm volatile("s_waitcnt vmcnt(0)" ::: "memory");   // wave's h-stores at L3
    if (lane == 0)
      __hip_atomic_store(&flags[((bg*16 + cg) << 2) + wv], epoch0 + (unsigned)t + 1u,
                         __ATOMIC_RELAXED, __HIP_MEMORY_SCOPE_AGENT);
    // enc store AFTER the announce: HBM ack off the protocol path; it drains
    // under the next step's poll window.
    *(f2v*)(enc + ((size_t)bglob * 256 + t) * 512 + j0 + up) = ev;
  }
}

// ---------------------------------------------------------------- softmax + cumsum + mask update (per batch)
__global__ __launch_bounds__(256, 4) void softmax_kernel(
    const float* __restrict__ part, const float* __restrict__ bb2, const float* __restrict__ gum,
    float* __restrict__ lout,
    float* __restrict__ sbf, float* __restrict__ sbout,
    float* __restrict__ logcum, float* __restrict__ maskf, float* __restrict__ maskout,
    int seg)
{
  __shared__ float red[256];
  __shared__ float cs[256];
  int b = blockIdx.x, t = threadIdx.x;
  float raw = 0.0f;
  #pragma unroll
  for (int s = 0; s < 8; s++) raw += part[s*16384 + b*256 + t];
  float lg  = (t == 0) ? NEG_INF_F : (raw + bb2[0]);
  lout[b*256 + t] = lg;
  float x = lg + gum[b*256 + t];   // TEMP_B = 1
  red[t] = x; __syncthreads();
  for (int o = 128; o > 0; o >>= 1){ if (t < o) red[t] = fmaxf(red[t], red[t+o]); __syncthreads(); }
  float mx = red[0]; __syncthreads();
  float e = __expf(x - mx);
  red[t] = e; __syncthreads();
  for (int o = 128; o > 0; o >>= 1){ if (t < o) red[t] += red[t+o]; __syncthreads(); }
  float s = red[0];
  float sb = e / s;
  sbf[b*256 + t] = sb;
  sbout[b*256 + t] = sb;
  cs[t] = sb; __syncthreads();
  for (int o = 1; o < 256; o <<= 1){
    float v = cs[t];
    if (t >= o) v += cs[t - o];
    __syncthreads();
    cs[t] = v;
    __syncthreads();
  }
  float lc = logf(cs[t] + 1e-17f);
  float acc = (seg == 0) ? lc : (logcum[b*256 + t] + lc);
  logcum[b*256 + t] = acc;
  float mk = __expf(acc);
  maskf[b*256 + t] = mk;
  maskout[b*256 + t] = mk;
}

// ---------------------------------------------------------------- one-hot(lengths-1) (last segment)
__global__ void onehot_kernel(const int* __restrict__ lengths,
                              float* __restrict__ sbf, float* __restrict__ sbout)
{
  int b = blockIdx.x, t = threadIdx.x;
  float v = (t == (lengths[b] - 1)) ? 1.0f : 0.0f;
  sbf[b*256 + t] = v;
  sbout[b*256 + t] = v;
}

// ---------------------------------------------------------------- readout = sum_t enc[b,t]*sb[b,t+1]
__global__ __launch_bounds__(256, 4) void readout_kernel(
    const float* __restrict__ enc, const float* __restrict__ sbf, float* __restrict__ ro)
{
  __shared__ float sb[256];
  int b = blockIdx.x, tid = threadIdx.x;
  sb[tid] = sbf[b*256 + tid];
  __syncthreads();
  float a0 = 0.0f, a1 = 0.0f;
  for (int t = 0; t < 255; t++){
    float m = sb[t + 1];
    f2v q = *(const f2v*)(enc + ((size_t)b*256 + t)*512 + tid*2);
    a0 += m * q[0];
    a1 += m * q[1];
  }
  ro[b*512 + tid*2]     = a0;
  ro[b*512 + tid*2 + 1] = a1;
}

// ---------------------------------------------------------------- z-head + decoder (per batch)
__global__ __launch_bounds__(256, 2) void zdec_kernel(
    const float* __restrict__ ro,
    const float* __restrict__ Wz1, const float* __restrict__ bz1,
    const float* __restrict__ Wz2, const float* __restrict__ bz2,
    const float* __restrict__ epsz,
    const float* __restrict__ Wd1, const float* __restrict__ bd1,
    const float* __restrict__ Wd2, const float* __restrict__ bd2,
    float* __restrict__ lzout, float* __restrict__ szout, float* __restrict__ recseg)
{
  __shared__ float r[512], hz[512], lz[128], sz[64], hd[512];
  int b = blockIdx.x, tid = threadIdx.x;
  r[tid]       = ro[b*512 + tid];
  r[tid + 256] = ro[b*512 + tid + 256];
  __syncthreads();
  {
    float a0 = bz1[tid], a1 = bz1[tid + 256];
    for (int i = 0; i < 512; i++){
      float ri = r[i];
      a0 += ri * Wz1[(size_t)i*512 + tid];
      a1 += ri * Wz1[(size_t)i*512 + tid + 256];
    }
    hz[tid]       = fmaxf(a0, 0.0f);
    hz[tid + 256] = fmaxf(a1, 0.0f);
  }
  __syncthreads();
  if (tid < 128){
    float a = bz2[tid];
    for (int i = 0; i < 512; i++) a += hz[i] * Wz2[(size_t)i*128 + tid];
    lz[tid] = a;
    lzout[b*128 + tid] = a;
  }
  __syncthreads();
  if (tid < 64){
    float mu = lz[tid], lv = lz[64 + tid];
    float v = mu + __expf(0.5f * lv) * epsz[b*64 + tid];
    sz[tid] = v;
    szout[b*64 + tid] = v;
  }
  __syncthreads();
  {
    float a0 = bd1[tid], a1 = bd1[tid + 256];
    for (int l = 0; l < 64; l++){
      float s = sz[l];
      a0 += s * Wd1[l*512 + tid];
      a1 += s * Wd1[l*512 + tid + 256];
    }
    hd[tid]       = fmaxf(a0, 0.0f);
    hd[tid + 256] = fmaxf(a1, 0.0f);
  }
  __syncthreads();
  {
    float a0 = bd2[tid];
    float a1 = (tid < 244) ? bd2[tid + 256] : 0.0f;
    for (int h = 0; h < 512; h++){
      float hh = hd[h];
      a0 += hh * Wd2[(size_t)h*500 + tid];
      if (tid < 244) a1 += hh * Wd2[(size_t)h*500 + tid + 256];
    }
    recseg[(size_t)b*128000 + tid] = a0;
    if (tid < 244) recseg[(size_t)b*128000 + tid + 256] = a1;
  }
}

// ---------------------------------------------------------------- broadcast recs row (b,0) -> rows (b,t>=1)
__global__ void rec_kernel(float* __restrict__ outr)
{
  int bidx = blockIdx.x;
  int b = bidx >> 8, t = bidx & 255;
  if (t == 0) return;
  int tid = threadIdx.x;
  if (tid < 125){
    f4v q = *(const f4v*)(outr + (size_t)b*128000 + tid*4);
    *(f4v*)(outr + ((size_t)b*256 + t)*500 + tid*4) = q;
  }
}

// ---------------------------------------------------------------- launcher
extern "C" void kernel_launch(void* const* d_in, const int* in_sizes, int n_in,
                              void* d_out, int out_size, void* d_ws, size_t ws_size,
                              hipStream_t stream)
{
  const int*   actions = (const int*)d_in[0];
  const int*   lengths = (const int*)d_in[1];
  const float* gumbel  = (const float*)d_in[2];
  const float* epsz    = (const float*)d_in[3];
  const float* embed   = (const float*)d_in[4];
  const float* Wx      = (const float*)d_in[5];
  const float* Wh      = (const float*)d_in[6];
  const float* b_lstm  = (const float*)d_in[7];
  const float* Wz1     = (const float*)d_in[8];
  const float* bz1     = (const float*)d_in[9];
  const float* Wz2     = (const float*)d_in[10];
  const float* bz2     = (const float*)d_in[11];
  const float* Wb1     = (const float*)d_in[12];
  const float* bb1     = (const float*)d_in[13];
  const float* Wb2     = (const float*)d_in[14];
  const float* bb2     = (const float*)d_in[15];
  const float* Wd1     = (const float*)d_in[16];
  const float* bd1     = (const float*)d_in[17];
  const float* Wd2     = (const float*)d_in[18];
  const float* bd2     = (const float*)d_in[19];
  float* out = (float*)d_out;

  float* r2      = out + (size_t)REC_OFF + 2*(size_t)REC_SEG;
  ubf*   P       = (ubf*)(r2 + SCR_P);
  ubf*   hbuf    = (ubf*)(r2 + SCR_HBUF);
  u32*   flags   = (u32*)(r2 + SCR_FLAGS);
  float* maskf   = r2 + SCR_MASKF;
  float* logcum  = r2 + SCR_LOGCUM;
  float* partf   = r2 + SCR_PART;
  float* sbf     = r2 + SCR_SBF;
  float* rof     = r2 + SCR_ROF;

  hipLaunchKernelGGL(init_kernel, dim3(1), dim3(256), 0, stream, flags);

  hipLaunchKernelGGL(gemm_kernel, dim3(16, 4), dim3(256), 0, stream,
                     (const void*)embed, 1, Wx, b_lstm, P,
                     (const float*)nullptr, (float*)nullptr,
                     512, 2048, 512, 0, 499);

  for (int seg = 0; seg < 3; ++seg){
    hipLaunchKernelGGL(lstm_kernel, dim3(64), dim3(256), 0, stream,
                       P, actions, Wh,
                       (seg == 0) ? (const float*)nullptr : maskf,
                       out + (size_t)seg * ENC_SEG, hbuf, flags, seg);
    const float* encc = out + (size_t)seg * ENC_SEG;
    if (seg < 2){
      hipLaunchKernelGGL(gemm_kernel, dim3(4, 128), dim3(256), 0, stream,
                         (const void*)encc, 1, Wb1, bb1, (ubf*)nullptr, Wb2, partf,
                         16384, 512, 512, 1, 16383);
      hipLaunchKernelGGL(softmax_kernel, dim3(64), dim3(256), 0, stream,
                         partf, bb2, gumbel + (size_t)seg * 16384,
                         out + LOGB_OFF + (size_t)seg * 16384,
                         sbf, out + SAMB_OFF + (size_t)seg * 16384,
                         logcum, maskf, out + MASK_OFF + (size_t)seg * 16384, seg);
    } else {
      hipLaunchKernelGGL(onehot_kernel, dim3(64), dim3(256), 0, stream,
                         lengths, sbf, out + SAMB_OFF + (size_t)seg * 16384);
    }
    hipLaunchKernelGGL(readout_kernel, dim3(64), dim3(256), 0, stream, encc, sbf, rof);
    hipLaunchKernelGGL(zdec_kernel, dim3(64), dim3(256), 0, stream,
                       rof, Wz1, bz1, Wz2, bz2, epsz + (size_t)seg * 4096,
                       Wd1, bd1, Wd2, bd2,
                       out + LOGZ_OFF + (size_t)seg * 8192,
                       out + SAMZ_OFF + (size_t)seg * 4096,
                       out + REC_OFF + (size_t)seg * REC_SEG);
    hipLaunchKernelGGL(rec_kernel, dim3(16384), dim3(128), 0, stream,
                       out + REC_OFF + (size_t)seg * REC_SEG);
  }
  (void)in_sizes; (void)n_in; (void)out_size; (void)d_ws; (void)ws_size;
}

// Round 5
// 2426.668 us; speedup vs baseline: 2.3674x; 1.3685x over previous
//
#include <hip/hip_runtime.h>
#include <cstdint>
#include <cstddef>

typedef unsigned short ubf;   // bf16 bit pattern (internal use only)
typedef unsigned int   u32;
typedef __attribute__((ext_vector_type(8))) short short8;
typedef __attribute__((ext_vector_type(4))) float f32x4;
typedef __attribute__((ext_vector_type(4))) float f4v;
typedef __attribute__((ext_vector_type(2))) float f2v;
typedef __attribute__((ext_vector_type(4))) unsigned short us4;

#define NEG_INF_F (-1000000000.0f)
#define FOURH 2048

// d_out element offsets in FLOAT32 elements (confirmed r8/r9).
#define ENC_SEG   8388608            // 64*256*512
#define REC_OFF   25165824
#define REC_SEG   8192000            // 64*256*500
#define MASK_OFF  49741824
#define LOGB_OFF  49774592
#define SAMB_OFF  49807360
#define LOGZ_OFF  49856512
#define SAMZ_OFF  49881088

// scratch inside recs[2] dead region (f32 elements from region base); r10/r12 layout.
#define SCR_P       0               // bf16[512][2048] = 524,288 f32
#define SCR_HBUF    524288          // bf16[2][4][16][512] = 32,768 f32
#define SCR_FLAGS   557056          // 1,024 f32 (64 flags x 16-dword padding)
#define SCR_MASKF   558080          // 16,384 f32
#define SCR_LOGCUM  574464          // 16,384 f32
#define SCR_PART    590848          // 131,072 f32
#define SCR_SBF     721920          // 16,384 f32
#define SCR_ROF     960000          // 32,768 f32 (stripe-free gap)

__device__ __forceinline__ float bf2f(ubf u){
  union { u32 i; float f; } v; v.i = ((u32)u) << 16; return v.f;
}
__device__ __forceinline__ ubf f2bf(float f){
  union { float f; u32 i; } v; v.f = f;
  u32 x = v.i;
  u32 r = (x + 0x7FFFu + ((x >> 16) & 1u)) >> 16;   // RNE
  return (ubf)r;
}
__device__ __forceinline__ float sigm(float x){
  return 1.0f / (1.0f + __expf(-x));
}
__device__ __forceinline__ float tanh_fast(float x){
  x = fminf(fmaxf(x, -20.0f), 20.0f);
  float e2 = __expf(2.0f * x);
  return (e2 - 1.0f) / (e2 + 1.0f);
}

// ---------------------------------------------------------------- init flags
__global__ void init_kernel(u32* flags){
  int tid = threadIdx.x;
  #pragma unroll
  for (int i = 0; i < 4; i++) flags[tid + i*256] = 0u;
}

// ---------------------------------------------------------------- GEMM (MFMA 16x16x32 bf16)
__global__ __launch_bounds__(256, 2) void gemm_kernel(
    const void* __restrict__ Aptr, int a_f32,
    const float* __restrict__ Bf, const float* __restrict__ bias,
    ubf* __restrict__ C, const float* __restrict__ wb2, float* __restrict__ part,
    int M, int N, int K, int relu, int mclamp)
{
  __shared__ __align__(16) ubf As[128*40];   // [128 rows][32 k + 8 pad]
  __shared__ __align__(16) ubf Bs[128*40];   // transposed: [128 n][32 k + 8 pad]
  int tid  = threadIdx.x;
  int bn   = blockIdx.x, bm = blockIdx.y;
  int w    = tid >> 6, lane = tid & 63, quad = lane >> 4, l16 = lane & 15;
  int wm   = w >> 1, wn = w & 1;

  f32x4 acc[4][4];
  #pragma unroll
  for (int i = 0; i < 4; i++)
    #pragma unroll
    for (int j = 0; j < 4; j++)
      #pragma unroll
      for (int r = 0; r < 4; r++) acc[i][j][r] = 0.0f;

  for (int k0 = 0; k0 < K; k0 += 32) {
    if (a_f32){
      const float* Af = (const float*)Aptr;
      #pragma unroll
      for (int h = 0; h < 4; h++){
        int v   = tid + h*256;          // 0..1023 float4 units
        int row = v >> 3, kc = (v & 7) * 4;
        int rm  = bm*128 + row;
        int ar  = rm < mclamp ? rm : mclamp;
        f4v q = *(const f4v*)(Af + (size_t)ar * K + k0 + kc);
        us4 s; s[0]=f2bf(q[0]); s[1]=f2bf(q[1]); s[2]=f2bf(q[2]); s[3]=f2bf(q[3]);
        *(us4*)&As[row*40 + kc] = s;
      }
    } else {
      const ubf* Ab = (const ubf*)Aptr;
      #pragma unroll
      for (int h = 0; h < 2; h++){
        int v   = tid + h*256;          // 0..511 vec8 units
        int row = v >> 2, kc = (v & 3) * 8;
        int rm  = bm*128 + row;
        int ar  = rm < mclamp ? rm : mclamp;
        uint4 q = *(const uint4*)(Ab + (size_t)ar * K + k0 + kc);
        *(uint4*)&As[row*40 + kc] = q;
      }
    }
    #pragma unroll
    for (int h = 0; h < 4; h++){
      int v  = tid + h*256;             // 0..1023 float4 units
      int kk = v >> 5, nn = (v & 31) * 4;
      f4v q = *(const f4v*)(Bf + (size_t)(k0 + kk) * N + bn*128 + nn);
      #pragma unroll
      for (int j = 0; j < 4; j++) Bs[(nn + j)*40 + kk] = f2bf(q[j]);
    }
    __syncthreads();
    short8 af[4], bfr[4];
    #pragma unroll
    for (int i = 0; i < 4; i++){
      int row = wm*64 + i*16 + l16;
      af[i]  = *(const short8*)&As[row*40 + quad*8];
      int col = wn*64 + i*16 + l16;
      bfr[i] = *(const short8*)&Bs[col*40 + quad*8];
    }
    #pragma unroll
    for (int i = 0; i < 4; i++)
      #pragma unroll
      for (int j = 0; j < 4; j++)
        acc[i][j] = __builtin_amdgcn_mfma_f32_16x16x32_bf16(af[i], bfr[j], acc[i][j], 0, 0, 0);
    __syncthreads();
  }
  if (!wb2){
    #pragma unroll
    for (int i = 0; i < 4; i++){
      #pragma unroll
      for (int j = 0; j < 4; j++){
        int n   = bn*128 + wn*64 + j*16 + l16;
        float bv = bias ? bias[n] : 0.0f;
        #pragma unroll
        for (int r = 0; r < 4; r++){
          int m   = bm*128 + wm*64 + i*16 + quad*4 + r;
          float vv = acc[i][j][r] + bv;
          if (relu) vv = fmaxf(vv, 0.0f);
          C[(size_t)m * N + n] = f2bf(vv);
        }
      }
    }
  } else {
    #pragma unroll
    for (int i = 0; i < 4; i++){
      f32x4 rp;
      #pragma unroll
      for (int r = 0; r < 4; r++) rp[r] = 0.0f;
      #pragma unroll
      for (int j = 0; j < 4; j++){
        int n   = bn*128 + wn*64 + j*16 + l16;
        float bv = bias[n];
        float wv = wb2[n];
        #pragma unroll
        for (int r = 0; r < 4; r++)
          rp[r] += fmaxf(acc[i][j][r] + bv, 0.0f) * wv;
      }
      #pragma unroll
      for (int off = 1; off < 16; off <<= 1)
        #pragma unroll
        for (int r = 0; r < 4; r++)
          rp[r] += __shfl_xor(rp[r], off, 64);
      if (l16 == 0){
        #pragma unroll
        for (int r = 0; r < 4; r++){
          int m = bm*128 + wm*64 + i*16 + quad*4 + r;
          part[(size_t)(bn*2 + wn)*16384 + m] = rp[r];
        }
      }
    }
  }
}

// ---------------------------------------------------------------- persistent masked-LSTM
// r15 = EXACT r12 restore (measured 610us — best protocol of 5 tried):
// per-thread poll of ONE padded flag + one-shot bulk load; writer does
// h sc1-stores -> threadfence_block + __syncthreads (vmcnt(0) drain) ->
// tid0 posts flag; enc store after the announce. r11/r13 (tagged data) and
// r14 (per-wave packed flags) both regressed — see session journal.
__global__ __launch_bounds__(256, 1) void lstm_kernel(
    const ubf* __restrict__ Pt,      // [512(V pad)][4H] bf16, includes b_lstm
    const int* __restrict__ actions, // [B][T]
    const float* __restrict__ Whf,   // [H][4H] f32
    const float* __restrict__ mask,  // [B][T] f32 or null (seg 0)
    float* __restrict__ enc,         // d_out + seg*ENC_SEG (f32)
    ubf* hbuf,                       // scratch: [2][4][16][512] bf16
    u32* flags,                      // scratch: [64]x16-dword-padded
    int seg)
{
  __shared__ __align__(16) ubf   htile[16*520];   // [16 b][512 + 8 pad]
  __shared__ __align__(16) ubf   ptile[16*136];   // [16 b][128 + 8 pad]
  __shared__ __align__(16) float ztile[16*132];   // [16 b][128 + 4 pad]

  int tid  = threadIdx.x;
  int wv   = tid >> 6;            // wave = gate index 0..3 (i,f,g,o)
  int lane = tid & 63, quad = lane >> 4, l16 = lane & 15;
  int bg   = blockIdx.x >> 4, cg = blockIdx.x & 15;
  int j0   = cg * 32;             // unit base

  // persistent Wh B-fragments: B[k][n], n = lane&15, k = quad*8+j
  short8 bfrag[2][16];
  #pragma unroll
  for (int h = 0; h < 2; h++){
    int col = wv*512 + j0 + h*16 + l16;
    #pragma unroll
    for (int kt = 0; kt < 16; kt++){
      short8 t8;
      #pragma unroll
      for (int j = 0; j < 8; j++){
        int k = kt*32 + quad*8 + j;
        t8[j] = (short)f2bf(Whf[(size_t)k * FOURH + col]);
      }
      bfrag[h][kt] = t8;
    }
  }

  float cst0 = 0.0f, cst1 = 0.0f;      // c-state for this thread's 2 (batch,unit) pairs
  int bl = tid >> 4;                   // local batch 0..15
  int up = (tid & 15) * 2;             // unit pair base within 32
  int bglob = bg*16 + bl;
  u32* htile32 = (u32*)htile;
  unsigned epoch0 = (unsigned)seg * 256u;
  u32* myflag = &flags[(bg*16 + (tid >> 4))*16];   // producer block this thread reads

  for (int t = 0; t < 256; ++t){
    // stage P tile [16 b][4 gates x 32 units], gathered by action id (L2-resident);
    // issued first so its latency hides under the flag poll below.
    {
      int act  = actions[(size_t)bglob * 256 + t];
      int colc = (tid & 15) * 8;
      int gate = colc >> 5, cw = colc & 31;
      uint4 q = *(const uint4*)(Pt + (size_t)act * FOURH + gate*512 + j0 + cw);
      *(uint4*)&ptile[bl*136 + colc] = q;
    }
    if (t > 0){
      // each thread polls the ONE producer flag it depends on, then loads its
      // 16 words (word index tid of 16 rows, all from block cg'=tid>>4).
      unsigned tgt = epoch0 + (unsigned)t;
      while (__hip_atomic_load(myflag, __ATOMIC_RELAXED, __HIP_MEMORY_SCOPE_AGENT) < tgt)
        __builtin_amdgcn_s_sleep(1);
      const u32* src = (const u32*)(hbuf + (size_t)(((t+1)&1)*4 + bg) * 16 * 512);
      u32 tmp[16];
      #pragma unroll
      for (int i = 0; i < 16; i++)
        tmp[i] = __hip_atomic_load(&src[tid + 256*i], __ATOMIC_RELAXED, __HIP_MEMORY_SCOPE_AGENT);
      #pragma unroll
      for (int i = 0; i < 16; i++)
        htile32[i*260 + tid] = tmp[i];     // row i = batch, 260 u32/row (padded)
    }
    __syncthreads();   // sync A: htile (and ptile) staged for this step

    f32x4 a0, a1;
    #pragma unroll
    for (int r = 0; r < 4; r++){ a0[r] = 0.0f; a1[r] = 0.0f; }
    if (t > 0){
      #pragma unroll
      for (int kt = 0; kt < 16; kt++){
        short8 af = *(const short8*)&htile[l16*520 + kt*32 + quad*8];
        a0 = __builtin_amdgcn_mfma_f32_16x16x32_bf16(af, bfrag[0][kt], a0, 0, 0, 0);
        a1 = __builtin_amdgcn_mfma_f32_16x16x32_bf16(af, bfrag[1][kt], a1, 0, 0, 0);
      }
    }
    // redistribute z via LDS so each thread gets matching i,f,g,o
    #pragma unroll
    for (int r = 0; r < 4; r++){
      ztile[(quad*4 + r)*132 + wv*32 + l16]      = a0[r];
      ztile[(quad*4 + r)*132 + wv*32 + 16 + l16] = a1[r];
    }
    __syncthreads();   // sync B: ztile ready for elementwise

    float m = mask ? mask[(size_t)bglob * 256 + t] : 1.0f;
    f2v ev;
    ubf hp[2];
    #pragma unroll
    for (int p = 0; p < 2; p++){
      int u = up + p;
      float zi = ztile[bl*132 +       u] + bf2f(ptile[bl*136 +       u]);
      float zf = ztile[bl*132 + 32 + u] + bf2f(ptile[bl*136 + 32 + u]);
      float zg = ztile[bl*132 + 64 + u] + bf2f(ptile[bl*136 + 64 + u]);
      float zo = ztile[bl*132 + 96 + u] + bf2f(ptile[bl*136 + 96 + u]);
      float is = sigm(zi), fs = sigm(zf), gt = tanh_fast(zg), os = sigm(zo);
      float cp = p ? cst1 : cst0;
      float cn = fs * cp + is * gt;
      float hn = os * tanh_fast(cn);
      ev[p] = hn;                       // enc records PRE-mask h (f32)
      float cm = m * cn;
      if (p) cst1 = cm; else cst0 = cm;
      hp[p] = f2bf(m * hn);             // masked h carried forward (bf16)
    }
    {
      u32 hword = (u32)hp[0] | ((u32)hp[1] << 16);
      u32* dst = (u32*)(hbuf + (size_t)((t&1)*4 + bg) * 16 * 512);
      __hip_atomic_store(&dst[(bl*512 + j0 + up) >> 1], hword,
                         __ATOMIC_RELAXED, __HIP_MEMORY_SCOPE_AGENT);
    }
    __threadfence_block();   // ordering intent only (block scope: no cache ops)
    __syncthreads();         // drain: vmcnt(0) -> sc1 h-stores committed at L3
    if (tid == 0)
      __hip_atomic_store(&flags[(bg*16 + cg)*16], epoch0 + (unsigned)t + 1u,
                         __ATOMIC_RELAXED, __HIP_MEMORY_SCOPE_AGENT);
    // enc store AFTER the announce: its HBM ack is off the protocol path;
    // it drains during the next step's poll window (covered by next drain).
    *(f2v*)(enc + ((size_t)bglob * 256 + t) * 512 + j0 + up) = ev;
  }
}

// ---------------------------------------------------------------- softmax + cumsum + mask update (per batch)
__global__ __launch_bounds__(256, 4) void softmax_kernel(
    const float* __restrict__ part, const float* __restrict__ bb2, const float* __restrict__ gum,
    float* __restrict__ lout,
    float* __restrict__ sbf, float* __restrict__ sbout,
    float* __restrict__ logcum, float* __restrict__ maskf, float* __restrict__ maskout,
    int seg)
{
  __shared__ float red[256];
  __shared__ float cs[256];
  int b = blockIdx.x, t = threadIdx.x;
  float raw = 0.0f;
  #pragma unroll
  for (int s = 0; s < 8; s++) raw += part[s*16384 + b*256 + t];
  float lg  = (t == 0) ? NEG_INF_F : (raw + bb2[0]);
  lout[b*256 + t] = lg;
  float x = lg + gum[b*256 + t];   // TEMP_B = 1
  red[t] = x; __syncthreads();
  for (int o = 128; o > 0; o >>= 1){ if (t < o) red[t] = fmaxf(red[t], red[t+o]); __syncthreads(); }
  float mx = red[0]; __syncthreads();
  float e = __expf(x - mx);
  red[t] = e; __syncthreads();
  for (int o = 128; o > 0; o >>= 1){ if (t < o) red[t] += red[t+o]; __syncthreads(); }
  float s = red[0];
  float sb = e / s;
  sbf[b*256 + t] = sb;
  sbout[b*256 + t] = sb;
  cs[t] = sb; __syncthreads();
  for (int o = 1; o < 256; o <<= 1){
    float v = cs[t];
    if (t >= o) v += cs[t - o];
    __syncthreads();
    cs[t] = v;
    __syncthreads();
  }
  float lc = logf(cs[t] + 1e-17f);
  float acc = (seg == 0) ? lc : (logcum[b*256 + t] + lc);
  logcum[b*256 + t] = acc;
  float mk = __expf(acc);
  maskf[b*256 + t] = mk;
  maskout[b*256 + t] = mk;
}

// ---------------------------------------------------------------- one-hot(lengths-1) (last segment)
__global__ void onehot_kernel(const int* __restrict__ lengths,
                              float* __restrict__ sbf, float* __restrict__ sbout)
{
  int b = blockIdx.x, t = threadIdx.x;
  float v = (t == (lengths[b] - 1)) ? 1.0f : 0.0f;
  sbf[b*256 + t] = v;
  sbout[b*256 + t] = v;
}

// ---------------------------------------------------------------- readout = sum_t enc[b,t]*sb[b,t+1]
// r15: t-split for latency hiding. Grid (64 b, 4 q); block covers units
// [q*128, q*128+128). 256 threads = 4 t-groups x 64 lanes; each thread
// accumulates 64 timesteps (g=3: 63) for its 2 units, LDS-reduce over the
// 4 t-groups. Serial depth 255 -> 64; blocks 64 -> 256.
__global__ __launch_bounds__(256, 4) void readout_kernel(
    const float* __restrict__ enc, const float* __restrict__ sbf, float* __restrict__ ro)
{
  __shared__ float sb[256];
  __shared__ f2v pa[4][64];
  int b = blockIdx.x, q = blockIdx.y, tid = threadIdx.x;
  sb[tid] = sbf[b*256 + tid];
  __syncthreads();
  int g = tid >> 6, l = tid & 63;
  int t0 = g*64, t1 = (g == 3) ? 255 : (g*64 + 64);
  const float* base = enc + ((size_t)b*256)*512 + q*128 + l*2;
  float a0 = 0.0f, a1 = 0.0f;
  for (int t = t0; t < t1; t++){
    float m = sb[t + 1];
    f2v v = *(const f2v*)(base + (size_t)t*512);
    a0 += m * v[0];
    a1 += m * v[1];
  }
  f2v p; p[0] = a0; p[1] = a1;
  pa[g][l] = p;
  __syncthreads();
  if (tid < 64){
    f2v s0 = pa[0][tid], s1 = pa[1][tid], s2 = pa[2][tid], s3 = pa[3][tid];
    ro[b*512 + q*128 + tid*2]     = s0[0] + s1[0] + s2[0] + s3[0];
    ro[b*512 + q*128 + tid*2 + 1] = s0[1] + s1[1] + s2[1] + s3[1];
  }
}

// ---------------------------------------------------------------- z-head + decoder (per batch)
// r15: 512 threads (8 waves) — 1 col/thread in the wide GEMV phases (was 2),
// halving per-thread serial depth and doubling latency-hiding wave count.
__global__ __launch_bounds__(512, 1) void zdec_kernel(
    const float* __restrict__ ro,
    const float* __restrict__ Wz1, const float* __restrict__ bz1,
    const float* __restrict__ Wz2, const float* __restrict__ bz2,
    const float* __restrict__ epsz,
    const float* __restrict__ Wd1, const float* __restrict__ bd1,
    const float* __restrict__ Wd2, const float* __restrict__ bd2,
    float* __restrict__ lzout, float* __restrict__ szout, float* __restrict__ recseg)
{
  __shared__ float r[512], hz[512], lz[128], sz[64], hd[512];
  int b = blockIdx.x, tid = threadIdx.x;
  r[tid] = ro[b*512 + tid];
  __syncthreads();
  {
    float a0 = bz1[tid];
    for (int i = 0; i < 512; i++)
      a0 += r[i] * Wz1[(size_t)i*512 + tid];
    hz[tid] = fmaxf(a0, 0.0f);
  }
  __syncthreads();
  if (tid < 128){
    float a = bz2[tid];
    for (int i = 0; i < 512; i++) a += hz[i] * Wz2[(size_t)i*128 + tid];
    lz[tid] = a;
    lzout[b*128 + tid] = a;
  }
  __syncthreads();
  if (tid < 64){
    float mu = lz[tid], lv = lz[64 + tid];
    float v = mu + __expf(0.5f * lv) * epsz[b*64 + tid];
    sz[tid] = v;
    szout[b*64 + tid] = v;
  }
  __syncthreads();
  {
    float a0 = bd1[tid];
    for (int l = 0; l < 64; l++)
      a0 += sz[l] * Wd1[l*512 + tid];
    hd[tid] = fmaxf(a0, 0.0f);
  }
  __syncthreads();
  if (tid < 500){
    float a0 = bd2[tid];
    for (int h = 0; h < 512; h++)
      a0 += hd[h] * Wd2[(size_t)h*500 + tid];
    recseg[(size_t)b*128000 + tid] = a0;
  }
}

// ---------------------------------------------------------------- broadcast recs row (b,0) -> rows (b,t>=1)
__global__ void rec_kernel(float* __restrict__ outr)
{
  int bidx = blockIdx.x;
  int b = bidx >> 8, t = bidx & 255;
  if (t == 0) return;
  int tid = threadIdx.x;
  if (tid < 125){
    f4v q = *(const f4v*)(outr + (size_t)b*128000 + tid*4);
    *(f4v*)(outr + ((size_t)b*256 + t)*500 + tid*4) = q;
  }
}

// ---------------------------------------------------------------- launcher
extern "C" void kernel_launch(void* const* d_in, const int* in_sizes, int n_in,
                              void* d_out, int out_size, void* d_ws, size_t ws_size,
                              hipStream_t stream)
{
  const int*   actions = (const int*)d_in[0];
  const int*   lengths = (const int*)d_in[1];
  const float* gumbel  = (const float*)d_in[2];
  const float* epsz    = (const float*)d_in[3];
  const float* embed   = (const float*)d_in[4];
  const float* Wx      = (const float*)d_in[5];
  const float* Wh      = (const float*)d_in[6];
  const float* b_lstm  = (const float*)d_in[7];
  const float* Wz1     = (const float*)d_in[8];
  const float* bz1     = (const float*)d_in[9];
  const float* Wz2     = (const float*)d_in[10];
  const float* bz2     = (const float*)d_in[11];
  const float* Wb1     = (const float*)d_in[12];
  const float* bb1     = (const float*)d_in[13];
  const float* Wb2     = (const float*)d_in[14];
  const float* bb2     = (const float*)d_in[15];
  const float* Wd1     = (const float*)d_in[16];
  const float* bd1     = (const float*)d_in[17];
  const float* Wd2     = (const float*)d_in[18];
  const float* bd2     = (const float*)d_in[19];
  float* out = (float*)d_out;

  float* r2      = out + (size_t)REC_OFF + 2*(size_t)REC_SEG;
  ubf*   P       = (ubf*)(r2 + SCR_P);
  ubf*   hbuf    = (ubf*)(r2 + SCR_HBUF);
  u32*   flags   = (u32*)(r2 + SCR_FLAGS);
  float* maskf   = r2 + SCR_MASKF;
  float* logcum  = r2 + SCR_LOGCUM;
  float* partf   = r2 + SCR_PART;
  float* sbf     = r2 + SCR_SBF;
  float* rof     = r2 + SCR_ROF;

  hipLaunchKernelGGL(init_kernel, dim3(1), dim3(256), 0, stream, flags);

  hipLaunchKernelGGL(gemm_kernel, dim3(16, 4), dim3(256), 0, stream,
                     (const void*)embed, 1, Wx, b_lstm, P,
                     (const float*)nullptr, (float*)nullptr,
                     512, 2048, 512, 0, 499);

  for (int seg = 0; seg < 3; ++seg){
    hipLaunchKernelGGL(lstm_kernel, dim3(64), dim3(256), 0, stream,
                       P, actions, Wh,
                       (seg == 0) ? (const float*)nullptr : maskf,
                       out + (size_t)seg * ENC_SEG, hbuf, flags, seg);
    const float* encc = out + (size_t)seg * ENC_SEG;
    if (seg < 2){
      hipLaunchKernelGGL(gemm_kernel, dim3(4, 128), dim3(256), 0, stream,
                         (const void*)encc, 1, Wb1, bb1, (ubf*)nullptr, Wb2, partf,
                         16384, 512, 512, 1, 16383);
      hipLaunchKernelGGL(softmax_kernel, dim3(64), dim3(256), 0, stream,
                         partf, bb2, gumbel + (size_t)seg * 16384,
                         out + LOGB_OFF + (size_t)seg * 16384,
                         sbf, out + SAMB_OFF + (size_t)seg * 16384,
                         logcum, maskf, out + MASK_OFF + (size_t)seg * 16384, seg);
    } else {
      hipLaunchKernelGGL(onehot_kernel, dim3(64), dim3(256), 0, stream,
                         lengths, sbf, out + SAMB_OFF + (size_t)seg * 16384);
    }
    hipLaunchKernelGGL(readout_kernel, dim3(64, 4), dim3(256), 0, stream, encc, sbf, rof);
    hipLaunchKernelGGL(zdec_kernel, dim3(64), dim3(512), 0, stream,
                       rof, Wz1, bz1, Wz2, bz2, epsz + (size_t)seg * 4096,
                       Wd1, bd1, Wd2, bd2,
                       out + LOGZ_OFF + (size_t)seg * 8192,
                       out + SAMZ_OFF + (size_t)seg * 4096,
                       out + REC_OFF + (size_t)seg * REC_SEG);
    hipLaunchKernelGGL(rec_kernel, dim3(16384), dim3(128), 0, stream,
                       out + REC_OFF + (size_t)seg * REC_SEG);
  }
  (void)in_sizes; (void)n_in; (void)out_size; (void)d_ws; (void)ws_size;
}

// Round 6
// 2391.971 us; speedup vs baseline: 2.4018x; 1.0145x over previous
//
#include <hip/hip_runtime.h>
#include <cstdint>
#include <cstddef>

typedef unsigned short ubf;   // bf16 bit pattern (internal use only)
typedef unsigned int   u32;
typedef __attribute__((ext_vector_type(8))) short short8;
typedef __attribute__((ext_vector_type(4))) float f32x4;
typedef __attribute__((ext_vector_type(4))) float f4v;
typedef __attribute__((ext_vector_type(2))) float f2v;
typedef __attribute__((ext_vector_type(4))) unsigned short us4;

#define NEG_INF_F (-1000000000.0f)
#define FOURH 2048

// d_out element offsets in FLOAT32 elements (confirmed r8/r9).
#define ENC_SEG   8388608            // 64*256*512
#define REC_OFF   25165824
#define REC_SEG   8192000            // 64*256*500
#define MASK_OFF  49741824
#define LOGB_OFF  49774592
#define SAMB_OFF  49807360
#define LOGZ_OFF  49856512
#define SAMZ_OFF  49881088

// scratch inside recs[2] dead region (f32 elements from region base); r10/r12 layout.
// SCR_ENCB (r16): bf16 copy of enc for the b-head gemm's A operand.
// Live only lstm_s -> gemm_s (seg 0,1); dead before zdec-seg2/rec-seg2
// overwrite recs[2] at the very end. Range 1,048,576..5,242,880 f32 — clear of
// all other scratch (max 992,768) and only overwritten by end-of-pipeline
// recs[2] writes, which happen after encb's last read.
#define SCR_P       0               // bf16[512][2048] = 524,288 f32
#define SCR_HBUF    524288          // bf16[2][4][16][512] = 32,768 f32
#define SCR_FLAGS   557056          // 1,024 f32 (64 flags x 16-dword padding)
#define SCR_MASKF   558080          // 16,384 f32
#define SCR_LOGCUM  574464          // 16,384 f32
#define SCR_PART    590848          // 131,072 f32
#define SCR_SBF     721920          // 16,384 f32
#define SCR_ROF     960000          // 32,768 f32 (stripe-free gap 896500..1024000)
#define SCR_ENCB    1048576         // bf16[16384][512] = 4,194,304 f32

__device__ __forceinline__ float bf2f(ubf u){
  union { u32 i; float f; } v; v.i = ((u32)u) << 16; return v.f;
}
__device__ __forceinline__ ubf f2bf(float f){
  union { float f; u32 i; } v; v.f = f;
  u32 x = v.i;
  u32 r = (x + 0x7FFFu + ((x >> 16) & 1u)) >> 16;   // RNE
  return (ubf)r;
}
__device__ __forceinline__ float sigm(float x){
  return 1.0f / (1.0f + __expf(-x));
}
__device__ __forceinline__ float tanh_fast(float x){
  x = fminf(fmaxf(x, -20.0f), 20.0f);
  float e2 = __expf(2.0f * x);
  return (e2 - 1.0f) / (e2 + 1.0f);
}

// ---------------------------------------------------------------- init flags
__global__ void init_kernel(u32* flags){
  int tid = threadIdx.x;
  #pragma unroll
  for (int i = 0; i < 4; i++) flags[tid + i*256] = 0u;
}

// ---------------------------------------------------------------- GEMM (MFMA 16x16x32 bf16)
__global__ __launch_bounds__(256, 2) void gemm_kernel(
    const void* __restrict__ Aptr, int a_f32,
    const float* __restrict__ Bf, const float* __restrict__ bias,
    ubf* __restrict__ C, const float* __restrict__ wb2, float* __restrict__ part,
    int M, int N, int K, int relu, int mclamp)
{
  __shared__ __align__(16) ubf As[128*40];   // [128 rows][32 k + 8 pad]
  __shared__ __align__(16) ubf Bs[128*40];   // transposed: [128 n][32 k + 8 pad]
  int tid  = threadIdx.x;
  int bn   = blockIdx.x, bm = blockIdx.y;
  int w    = tid >> 6, lane = tid & 63, quad = lane >> 4, l16 = lane & 15;
  int wm   = w >> 1, wn = w & 1;

  f32x4 acc[4][4];
  #pragma unroll
  for (int i = 0; i < 4; i++)
    #pragma unroll
    for (int j = 0; j < 4; j++)
      #pragma unroll
      for (int r = 0; r < 4; r++) acc[i][j][r] = 0.0f;

  for (int k0 = 0; k0 < K; k0 += 32) {
    if (a_f32){
      const float* Af = (const float*)Aptr;
      #pragma unroll
      for (int h = 0; h < 4; h++){
        int v   = tid + h*256;          // 0..1023 float4 units
        int row = v >> 3, kc = (v & 7) * 4;
        int rm  = bm*128 + row;
        int ar  = rm < mclamp ? rm : mclamp;
        f4v q = *(const f4v*)(Af + (size_t)ar * K + k0 + kc);
        us4 s; s[0]=f2bf(q[0]); s[1]=f2bf(q[1]); s[2]=f2bf(q[2]); s[3]=f2bf(q[3]);
        *(us4*)&As[row*40 + kc] = s;
      }
    } else {
      const ubf* Ab = (const ubf*)Aptr;
      #pragma unroll
      for (int h = 0; h < 2; h++){
        int v   = tid + h*256;          // 0..511 vec8 units
        int row = v >> 2, kc = (v & 3) * 8;
        int rm  = bm*128 + row;
        int ar  = rm < mclamp ? rm : mclamp;
        uint4 q = *(const uint4*)(Ab + (size_t)ar * K + k0 + kc);
        *(uint4*)&As[row*40 + kc] = q;
      }
    }
    #pragma unroll
    for (int h = 0; h < 4; h++){
      int v  = tid + h*256;             // 0..1023 float4 units
      int kk = v >> 5, nn = (v & 31) * 4;
      f4v q = *(const f4v*)(Bf + (size_t)(k0 + kk) * N + bn*128 + nn);
      #pragma unroll
      for (int j = 0; j < 4; j++) Bs[(nn + j)*40 + kk] = f2bf(q[j]);
    }
    __syncthreads();
    short8 af[4], bfr[4];
    #pragma unroll
    for (int i = 0; i < 4; i++){
      int row = wm*64 + i*16 + l16;
      af[i]  = *(const short8*)&As[row*40 + quad*8];
      int col = wn*64 + i*16 + l16;
      bfr[i] = *(const short8*)&Bs[col*40 + quad*8];
    }
    #pragma unroll
    for (int i = 0; i < 4; i++)
      #pragma unroll
      for (int j = 0; j < 4; j++)
        acc[i][j] = __builtin_amdgcn_mfma_f32_16x16x32_bf16(af[i], bfr[j], acc[i][j], 0, 0, 0);
    __syncthreads();
  }
  if (!wb2){
    #pragma unroll
    for (int i = 0; i < 4; i++){
      #pragma unroll
      for (int j = 0; j < 4; j++){
        int n   = bn*128 + wn*64 + j*16 + l16;
        float bv = bias ? bias[n] : 0.0f;
        #pragma unroll
        for (int r = 0; r < 4; r++){
          int m   = bm*128 + wm*64 + i*16 + quad*4 + r;
          float vv = acc[i][j][r] + bv;
          if (relu) vv = fmaxf(vv, 0.0f);
          C[(size_t)m * N + n] = f2bf(vv);
        }
      }
    }
  } else {
    #pragma unroll
    for (int i = 0; i < 4; i++){
      f32x4 rp;
      #pragma unroll
      for (int r = 0; r < 4; r++) rp[r] = 0.0f;
      #pragma unroll
      for (int j = 0; j < 4; j++){
        int n   = bn*128 + wn*64 + j*16 + l16;
        float bv = bias[n];
        float wv = wb2[n];
        #pragma unroll
        for (int r = 0; r < 4; r++)
          rp[r] += fmaxf(acc[i][j][r] + bv, 0.0f) * wv;
      }
      #pragma unroll
      for (int off = 1; off < 16; off <<= 1)
        #pragma unroll
        for (int r = 0; r < 4; r++)
          rp[r] += __shfl_xor(rp[r], off, 64);
      if (l16 == 0){
        #pragma unroll
        for (int r = 0; r < 4; r++){
          int m = bm*128 + wm*64 + i*16 + quad*4 + r;
          part[(size_t)(bn*2 + wn)*16384 + m] = rp[r];
        }
      }
    }
  }
}

// ---------------------------------------------------------------- persistent masked-LSTM
// r16 = r12/r15 protocol byte-identical (measured 608-610us; best of 5
// protocols tried — see journal). Single addition: packed bf16 enc store
// (encb) after the flag post, off the protocol critical path, feeding the
// b-head gemm's bf16 A operand. Values identical to gemm's own f32->bf16
// conversion (same RNE), so numerics are unchanged.
__global__ __launch_bounds__(256, 1) void lstm_kernel(
    const ubf* __restrict__ Pt,      // [512(V pad)][4H] bf16, includes b_lstm
    const int* __restrict__ actions, // [B][T]
    const float* __restrict__ Whf,   // [H][4H] f32
    const float* __restrict__ mask,  // [B][T] f32 or null (seg 0)
    float* __restrict__ enc,         // d_out + seg*ENC_SEG (f32)
    ubf* __restrict__ encb,          // scratch bf16 enc copy or null (seg 2)
    ubf* hbuf,                       // scratch: [2][4][16][512] bf16
    u32* flags,                      // scratch: [64]x16-dword-padded
    int seg)
{
  __shared__ __align__(16) ubf   htile[16*520];   // [16 b][512 + 8 pad]
  __shared__ __align__(16) ubf   ptile[16*136];   // [16 b][128 + 8 pad]
  __shared__ __align__(16) float ztile[16*132];   // [16 b][128 + 4 pad]

  int tid  = threadIdx.x;
  int wv   = tid >> 6;            // wave = gate index 0..3 (i,f,g,o)
  int lane = tid & 63, quad = lane >> 4, l16 = lane & 15;
  int bg   = blockIdx.x >> 4, cg = blockIdx.x & 15;
  int j0   = cg * 32;             // unit base

  // persistent Wh B-fragments: B[k][n], n = lane&15, k = quad*8+j
  short8 bfrag[2][16];
  #pragma unroll
  for (int h = 0; h < 2; h++){
    int col = wv*512 + j0 + h*16 + l16;
    #pragma unroll
    for (int kt = 0; kt < 16; kt++){
      short8 t8;
      #pragma unroll
      for (int j = 0; j < 8; j++){
        int k = kt*32 + quad*8 + j;
        t8[j] = (short)f2bf(Whf[(size_t)k * FOURH + col]);
      }
      bfrag[h][kt] = t8;
    }
  }

  float cst0 = 0.0f, cst1 = 0.0f;      // c-state for this thread's 2 (batch,unit) pairs
  int bl = tid >> 4;                   // local batch 0..15
  int up = (tid & 15) * 2;             // unit pair base within 32
  int bglob = bg*16 + bl;
  u32* htile32 = (u32*)htile;
  unsigned epoch0 = (unsigned)seg * 256u;
  u32* myflag = &flags[(bg*16 + (tid >> 4))*16];   // producer block this thread reads

  for (int t = 0; t < 256; ++t){
    // stage P tile [16 b][4 gates x 32 units], gathered by action id (L2-resident);
    // issued first so its latency hides under the flag poll below.
    {
      int act  = actions[(size_t)bglob * 256 + t];
      int colc = (tid & 15) * 8;
      int gate = colc >> 5, cw = colc & 31;
      uint4 q = *(const uint4*)(Pt + (size_t)act * FOURH + gate*512 + j0 + cw);
      *(uint4*)&ptile[bl*136 + colc] = q;
    }
    if (t > 0){
      // each thread polls the ONE producer flag it depends on, then loads its
      // 16 words (word index tid of 16 rows, all from block cg'=tid>>4).
      unsigned tgt = epoch0 + (unsigned)t;
      while (__hip_atomic_load(myflag, __ATOMIC_RELAXED, __HIP_MEMORY_SCOPE_AGENT) < tgt)
        __builtin_amdgcn_s_sleep(1);
      const u32* src = (const u32*)(hbuf + (size_t)(((t+1)&1)*4 + bg) * 16 * 512);
      u32 tmp[16];
      #pragma unroll
      for (int i = 0; i < 16; i++)
        tmp[i] = __hip_atomic_load(&src[tid + 256*i], __ATOMIC_RELAXED, __HIP_MEMORY_SCOPE_AGENT);
      #pragma unroll
      for (int i = 0; i < 16; i++)
        htile32[i*260 + tid] = tmp[i];     // row i = batch, 260 u32/row (padded)
    }
    __syncthreads();   // sync A: htile (and ptile) staged for this step

    f32x4 a0, a1;
    #pragma unroll
    for (int r = 0; r < 4; r++){ a0[r] = 0.0f; a1[r] = 0.0f; }
    if (t > 0){
      #pragma unroll
      for (int kt = 0; kt < 16; kt++){
        short8 af = *(const short8*)&htile[l16*520 + kt*32 + quad*8];
        a0 = __builtin_amdgcn_mfma_f32_16x16x32_bf16(af, bfrag[0][kt], a0, 0, 0, 0);
        a1 = __builtin_amdgcn_mfma_f32_16x16x32_bf16(af, bfrag[1][kt], a1, 0, 0, 0);
      }
    }
    // redistribute z via LDS so each thread gets matching i,f,g,o
    #pragma unroll
    for (int r = 0; r < 4; r++){
      ztile[(quad*4 + r)*132 + wv*32 + l16]      = a0[r];
      ztile[(quad*4 + r)*132 + wv*32 + 16 + l16] = a1[r];
    }
    __syncthreads();   // sync B: ztile ready for elementwise

    float m = mask ? mask[(size_t)bglob * 256 + t] : 1.0f;
    f2v ev;
    ubf hp[2];
    #pragma unroll
    for (int p = 0; p < 2; p++){
      int u = up + p;
      float zi = ztile[bl*132 +       u] + bf2f(ptile[bl*136 +       u]);
      float zf = ztile[bl*132 + 32 + u] + bf2f(ptile[bl*136 + 32 + u]);
      float zg = ztile[bl*132 + 64 + u] + bf2f(ptile[bl*136 + 64 + u]);
      float zo = ztile[bl*132 + 96 + u] + bf2f(ptile[bl*136 + 96 + u]);
      float is = sigm(zi), fs = sigm(zf), gt = tanh_fast(zg), os = sigm(zo);
      float cp = p ? cst1 : cst0;
      float cn = fs * cp + is * gt;
      float hn = os * tanh_fast(cn);
      ev[p] = hn;                       // enc records PRE-mask h (f32)
      float cm = m * cn;
      if (p) cst1 = cm; else cst0 = cm;
      hp[p] = f2bf(m * hn);             // masked h carried forward (bf16)
    }
    {
      u32 hword = (u32)hp[0] | ((u32)hp[1] << 16);
      u32* dst = (u32*)(hbuf + (size_t)((t&1)*4 + bg) * 16 * 512);
      __hip_atomic_store(&dst[(bl*512 + j0 + up) >> 1], hword,
                         __ATOMIC_RELAXED, __HIP_MEMORY_SCOPE_AGENT);
    }
    __threadfence_block();   // ordering intent only (block scope: no cache ops)
    __syncthreads();         // drain: vmcnt(0) -> sc1 h-stores committed at L3
    if (tid == 0)
      __hip_atomic_store(&flags[(bg*16 + cg)*16], epoch0 + (unsigned)t + 1u,
                         __ATOMIC_RELAXED, __HIP_MEMORY_SCOPE_AGENT);
    // enc stores AFTER the announce: HBM acks off the protocol path; they
    // drain during the next step's poll window (covered by next drain).
    *(f2v*)(enc + ((size_t)bglob * 256 + t) * 512 + j0 + up) = ev;
    if (encb){
      u32 ebw = (u32)f2bf(ev[0]) | ((u32)f2bf(ev[1]) << 16);
      *(u32*)&encb[((size_t)bglob * 256 + t) * 512 + j0 + up] = ebw;
    }
  }
}

// ---------------------------------------------------------------- softmax + cumsum + mask update (per batch)
__global__ __launch_bounds__(256, 4) void softmax_kernel(
    const float* __restrict__ part, const float* __restrict__ bb2, const float* __restrict__ gum,
    float* __restrict__ lout,
    float* __restrict__ sbf, float* __restrict__ sbout,
    float* __restrict__ logcum, float* __restrict__ maskf, float* __restrict__ maskout,
    int seg)
{
  __shared__ float red[256];
  __shared__ float cs[256];
  int b = blockIdx.x, t = threadIdx.x;
  float raw = 0.0f;
  #pragma unroll
  for (int s = 0; s < 8; s++) raw += part[s*16384 + b*256 + t];
  float lg  = (t == 0) ? NEG_INF_F : (raw + bb2[0]);
  lout[b*256 + t] = lg;
  float x = lg + gum[b*256 + t];   // TEMP_B = 1
  red[t] = x; __syncthreads();
  for (int o = 128; o > 0; o >>= 1){ if (t < o) red[t] = fmaxf(red[t], red[t+o]); __syncthreads(); }
  float mx = red[0]; __syncthreads();
  float e = __expf(x - mx);
  red[t] = e; __syncthreads();
  for (int o = 128; o > 0; o >>= 1){ if (t < o) red[t] += red[t+o]; __syncthreads(); }
  float s = red[0];
  float sb = e / s;
  sbf[b*256 + t] = sb;
  sbout[b*256 + t] = sb;
  cs[t] = sb; __syncthreads();
  for (int o = 1; o < 256; o <<= 1){
    float v = cs[t];
    if (t >= o) v += cs[t - o];
    __syncthreads();
    cs[t] = v;
    __syncthreads();
  }
  float lc = logf(cs[t] + 1e-17f);
  float acc = (seg == 0) ? lc : (logcum[b*256 + t] + lc);
  logcum[b*256 + t] = acc;
  float mk = __expf(acc);
  maskf[b*256 + t] = mk;
  maskout[b*256 + t] = mk;
}

// ---------------------------------------------------------------- one-hot(lengths-1) (last segment)
__global__ void onehot_kernel(const int* __restrict__ lengths,
                              float* __restrict__ sbf, float* __restrict__ sbout)
{
  int b = blockIdx.x, t = threadIdx.x;
  float v = (t == (lengths[b] - 1)) ? 1.0f : 0.0f;
  sbf[b*256 + t] = v;
  sbout[b*256 + t] = v;
}

// ---------------------------------------------------------------- readout = sum_t enc[b,t]*sb[b,t+1]
// r15 shape (kept): grid (64 b, 4 q); 256 threads = 4 t-groups x 64 lanes;
// serial depth 255 -> 64; LDS-reduce over t-groups.
__global__ __launch_bounds__(256, 4) void readout_kernel(
    const float* __restrict__ enc, const float* __restrict__ sbf, float* __restrict__ ro)
{
  __shared__ float sb[256];
  __shared__ f2v pa[4][64];
  int b = blockIdx.x, q = blockIdx.y, tid = threadIdx.x;
  sb[tid] = sbf[b*256 + tid];
  __syncthreads();
  int g = tid >> 6, l = tid & 63;
  int t0 = g*64, t1 = (g == 3) ? 255 : (g*64 + 64);
  const float* base = enc + ((size_t)b*256)*512 + q*128 + l*2;
  float a0 = 0.0f, a1 = 0.0f;
  for (int t = t0; t < t1; t++){
    float m = sb[t + 1];
    f2v v = *(const f2v*)(base + (size_t)t*512);
    a0 += m * v[0];
    a1 += m * v[1];
  }
  f2v p; p[0] = a0; p[1] = a1;
  pa[g][l] = p;
  __syncthreads();
  if (tid < 64){
    f2v s0 = pa[0][tid], s1 = pa[1][tid], s2 = pa[2][tid], s3 = pa[3][tid];
    ro[b*512 + q*128 + tid*2]     = s0[0] + s1[0] + s2[0] + s3[0];
    ro[b*512 + q*128 + tid*2 + 1] = s0[1] + s1[1] + s2[1] + s3[1];
  }
}

// ---------------------------------------------------------------- z-head + decoder (per batch)
// r15 shape (512 threads) + r16: optional fused broadcast of the rec row to
// all 256 timesteps (bcast=1 for seg 0/1 — their rec regions hold no live
// scratch, so the whole-region write is race-free; seg 2 keeps the separate
// rec_kernel because scratch (ro) lives inside recs[2] and another block's
// broadcast could overwrite it while still being read — G16).
__global__ __launch_bounds__(512, 1) void zdec_kernel(
    const float* __restrict__ ro,
    const float* __restrict__ Wz1, const float* __restrict__ bz1,
    const float* __restrict__ Wz2, const float* __restrict__ bz2,
    const float* __restrict__ epsz,
    const float* __restrict__ Wd1, const float* __restrict__ bd1,
    const float* __restrict__ Wd2, const float* __restrict__ bd2,
    float* __restrict__ lzout, float* __restrict__ szout, float* __restrict__ recseg,
    int bcast)
{
  __shared__ float r[512], hz[512], lz[128], sz[64], hd[512];
  int b = blockIdx.x, tid = threadIdx.x;
  r[tid] = ro[b*512 + tid];
  __syncthreads();
  {
    float a0 = bz1[tid];
    for (int i = 0; i < 512; i++)
      a0 += r[i] * Wz1[(size_t)i*512 + tid];
    hz[tid] = fmaxf(a0, 0.0f);
  }
  __syncthreads();
  if (tid < 128){
    float a = bz2[tid];
    for (int i = 0; i < 512; i++) a += hz[i] * Wz2[(size_t)i*128 + tid];
    lz[tid] = a;
    lzout[b*128 + tid] = a;
  }
  __syncthreads();
  if (tid < 64){
    float mu = lz[tid], lv = lz[64 + tid];
    float v = mu + __expf(0.5f * lv) * epsz[b*64 + tid];
    sz[tid] = v;
    szout[b*64 + tid] = v;
  }
  __syncthreads();
  {
    float a0 = bd1[tid];
    for (int l = 0; l < 64; l++)
      a0 += sz[l] * Wd1[l*512 + tid];
    hd[tid] = fmaxf(a0, 0.0f);
  }
  __syncthreads();
  if (tid < 500){
    float a0 = bd2[tid];
    for (int h = 0; h < 512; h++)
      a0 += hd[h] * Wd2[(size_t)h*500 + tid];
    if (bcast){
      for (int t = 0; t < 256; t++)
        recseg[(size_t)b*128000 + (size_t)t*500 + tid] = a0;
    } else {
      recseg[(size_t)b*128000 + tid] = a0;
    }
  }
}

// ---------------------------------------------------------------- broadcast recs row (b,0) -> rows (b,t>=1)
__global__ void rec_kernel(float* __restrict__ outr)
{
  int bidx = blockIdx.x;
  int b = bidx >> 8, t = bidx & 255;
  if (t == 0) return;
  int tid = threadIdx.x;
  if (tid < 125){
    f4v q = *(const f4v*)(outr + (size_t)b*128000 + tid*4);
    *(f4v*)(outr + ((size_t)b*256 + t)*500 + tid*4) = q;
  }
}

// ---------------------------------------------------------------- launcher
extern "C" void kernel_launch(void* const* d_in, const int* in_sizes, int n_in,
                              void* d_out, int out_size, void* d_ws, size_t ws_size,
                              hipStream_t stream)
{
  const int*   actions = (const int*)d_in[0];
  const int*   lengths = (const int*)d_in[1];
  const float* gumbel  = (const float*)d_in[2];
  const float* epsz    = (const float*)d_in[3];
  const float* embed   = (const float*)d_in[4];
  const float* Wx      = (const float*)d_in[5];
  const float* Wh      = (const float*)d_in[6];
  const float* b_lstm  = (const float*)d_in[7];
  const float* Wz1     = (const float*)d_in[8];
  const float* bz1     = (const float*)d_in[9];
  const float* Wz2     = (const float*)d_in[10];
  const float* bz2     = (const float*)d_in[11];
  const float* Wb1     = (const float*)d_in[12];
  const float* bb1     = (const float*)d_in[13];
  const float* Wb2     = (const float*)d_in[14];
  const float* bb2     = (const float*)d_in[15];
  const float* Wd1     = (const float*)d_in[16];
  const float* bd1     = (const float*)d_in[17];
  const float* Wd2     = (const float*)d_in[18];
  const float* bd2     = (const float*)d_in[19];
  float* out = (float*)d_out;

  float* r2      = out + (size_t)REC_OFF + 2*(size_t)REC_SEG;
  ubf*   P       = (ubf*)(r2 + SCR_P);
  ubf*   hbuf    = (ubf*)(r2 + SCR_HBUF);
  u32*   flags   = (u32*)(r2 + SCR_FLAGS);
  float* maskf   = r2 + SCR_MASKF;
  float* logcum  = r2 + SCR_LOGCUM;
  float* partf   = r2 + SCR_PART;
  float* sbf     = r2 + SCR_SBF;
  float* rof     = r2 + SCR_ROF;
  ubf*   encb    = (ubf*)(r2 + SCR_ENCB);

  hipLaunchKernelGGL(init_kernel, dim3(1), dim3(256), 0, stream, flags);

  hipLaunchKernelGGL(gemm_kernel, dim3(16, 4), dim3(256), 0, stream,
                     (const void*)embed, 1, Wx, b_lstm, P,
                     (const float*)nullptr, (float*)nullptr,
                     512, 2048, 512, 0, 499);

  for (int seg = 0; seg < 3; ++seg){
    hipLaunchKernelGGL(lstm_kernel, dim3(64), dim3(256), 0, stream,
                       P, actions, Wh,
                       (seg == 0) ? (const float*)nullptr : maskf,
                       out + (size_t)seg * ENC_SEG,
                       (seg < 2) ? encb : (ubf*)nullptr,
                       hbuf, flags, seg);
    const float* encc = out + (size_t)seg * ENC_SEG;
    if (seg < 2){
      hipLaunchKernelGGL(gemm_kernel, dim3(4, 128), dim3(256), 0, stream,
                         (const void*)encb, 0, Wb1, bb1, (ubf*)nullptr, Wb2, partf,
                         16384, 512, 512, 1, 16383);
      hipLaunchKernelGGL(softmax_kernel, dim3(64), dim3(256), 0, stream,
                         partf, bb2, gumbel + (size_t)seg * 16384,
                         out + LOGB_OFF + (size_t)seg * 16384,
                         sbf, out + SAMB_OFF + (size_t)seg * 16384,
                         logcum, maskf, out + MASK_OFF + (size_t)seg * 16384, seg);
    } else {
      hipLaunchKernelGGL(onehot_kernel, dim3(64), dim3(256), 0, stream,
                         lengths, sbf, out + SAMB_OFF + (size_t)seg * 16384);
    }
    hipLaunchKernelGGL(readout_kernel, dim3(64, 4), dim3(256), 0, stream, encc, sbf, rof);
    hipLaunchKernelGGL(zdec_kernel, dim3(64), dim3(512), 0, stream,
                       rof, Wz1, bz1, Wz2, bz2, epsz + (size_t)seg * 4096,
                       Wd1, bd1, Wd2, bd2,
                       out + LOGZ_OFF + (size_t)seg * 8192,
                       out + SAMZ_OFF + (size_t)seg * 4096,
                       out + REC_OFF + (size_t)seg * REC_SEG,
                       (seg < 2) ? 1 : 0);
    if (seg == 2)
      hipLaunchKernelGGL(rec_kernel, dim3(16384), dim3(128), 0, stream,
                         out + REC_OFF + (size_t)seg * REC_SEG);
  }
  (void)in_sizes; (void)n_in; (void)out_size; (void)d_ws; (void)ws_size;
}